// Round 3
// baseline (1237.749 us; speedup 1.0000x reference)
//
#include <hip/hip_runtime.h>
#include <cstdint>
#include <cstddef>

#define B   32
#define N   4096
#define NP  512
#define NS  16
#define C   256
#define CIN 259
#define HID 128
#define SB  (NP*NS)      // 8192 columns per batch
#define S   (B*SB)       // 262144 total columns
#define EPSF 1e-5f

#define FPS_BLOCKS 32
#define TR_BLOCKS  (B*256)   // 8192 transpose tiles
#define PREP_BLOCKS 64

typedef __attribute__((ext_vector_type(8))) short short8;
typedef __attribute__((ext_vector_type(4))) float floatx4;

__device__ __forceinline__ float bf2f(unsigned short u) {
    return __uint_as_float(((unsigned)u) << 16);
}
__device__ __forceinline__ unsigned short f2bf(float f) {
    unsigned u = __float_as_uint(f);
    return (unsigned short)((u + 0x7FFFu + ((u >> 16) & 1u)) >> 16);
}

// wave64 max of nonneg-float bits via DPP (VALU pipe, no LDS crossbar), result uniform
__device__ __forceinline__ int wave_max_i32(int x) {
    int y;
    y = __builtin_amdgcn_update_dpp(0, x, 0x111, 0xf, 0xf, true); x = (y > x) ? y : x;
    y = __builtin_amdgcn_update_dpp(0, x, 0x112, 0xf, 0xf, true); x = (y > x) ? y : x;
    y = __builtin_amdgcn_update_dpp(0, x, 0x114, 0xf, 0xf, true); x = (y > x) ? y : x;
    y = __builtin_amdgcn_update_dpp(0, x, 0x118, 0xf, 0xf, true); x = (y > x) ? y : x;
    y = __builtin_amdgcn_update_dpp(0, x, 0x142, 0xa, 0xf, true); x = (y > x) ? y : x;
    y = __builtin_amdgcn_update_dpp(0, x, 0x143, 0xc, 0xf, true); x = (y > x) ? y : x;
    return __builtin_amdgcn_readlane(x, 63);
}
__device__ __forceinline__ unsigned wave_max_u32(unsigned x) {
    unsigned y;
    y = (unsigned)__builtin_amdgcn_update_dpp(0, (int)x, 0x111, 0xf, 0xf, true); x = (y > x) ? y : x;
    y = (unsigned)__builtin_amdgcn_update_dpp(0, (int)x, 0x112, 0xf, 0xf, true); x = (y > x) ? y : x;
    y = (unsigned)__builtin_amdgcn_update_dpp(0, (int)x, 0x114, 0xf, 0xf, true); x = (y > x) ? y : x;
    y = (unsigned)__builtin_amdgcn_update_dpp(0, (int)x, 0x118, 0xf, 0xf, true); x = (y > x) ? y : x;
    y = (unsigned)__builtin_amdgcn_update_dpp(0, (int)x, 0x142, 0xa, 0xf, true); x = (y > x) ? y : x;
    y = (unsigned)__builtin_amdgcn_update_dpp(0, (int)x, 0x143, 0xc, 0xf, true); x = (y > x) ? y : x;
    return (unsigned)__builtin_amdgcn_readlane((int)x, 63);
}

__device__ __forceinline__ unsigned long long umax64(unsigned long long a, unsigned long long b) {
    return (b > a) ? b : a;
}

// sum over each 16-lane row; lanes with (lane&15)==15 hold the full row sum
__device__ __forceinline__ float row16_sum(float x) {
    float y;
    y = __int_as_float(__builtin_amdgcn_update_dpp(0, __float_as_int(x), 0x111, 0xf, 0xf, true)); x += y;
    y = __int_as_float(__builtin_amdgcn_update_dpp(0, __float_as_int(x), 0x112, 0xf, 0xf, true)); x += y;
    y = __int_as_float(__builtin_amdgcn_update_dpp(0, __float_as_int(x), 0x114, 0xf, 0xf, true)); x += y;
    y = __int_as_float(__builtin_amdgcn_update_dpp(0, __float_as_int(x), 0x118, 0xf, 0xf, true)); x += y;
    return x;
}
// max over each 16-lane row (sign-safe: invalid lanes keep old value); lane&15==15 holds row max
__device__ __forceinline__ float row16_max(float x) {
    int xi = __float_as_int(x);
    float y;
    y = __int_as_float(__builtin_amdgcn_update_dpp(xi, xi, 0x111, 0xf, 0xf, false)); x = fmaxf(x, y); xi = __float_as_int(x);
    y = __int_as_float(__builtin_amdgcn_update_dpp(xi, xi, 0x112, 0xf, 0xf, false)); x = fmaxf(x, y); xi = __float_as_int(x);
    y = __int_as_float(__builtin_amdgcn_update_dpp(xi, xi, 0x114, 0xf, 0xf, false)); x = fmaxf(x, y); xi = __float_as_int(x);
    y = __int_as_float(__builtin_amdgcn_update_dpp(xi, xi, 0x118, 0xf, 0xf, false)); x = fmaxf(x, y);
    return x;
}

// ---------------- fused front: FPS + feat transpose(bf16) + weight prep(bf16) ----------------
__global__ __launch_bounds__(512) void fused_front_kernel(
        const float* __restrict__ seed, const float* __restrict__ xyz,
        const float* __restrict__ feat, const float* __restrict__ w1,
        const float* __restrict__ w2, const float* __restrict__ w3,
        unsigned short* __restrict__ featT, unsigned short* __restrict__ w1fb,
        unsigned short* __restrict__ w2b, unsigned short* __restrict__ w3b,
        float* __restrict__ stats, int* __restrict__ inds,
        float* __restrict__ out_newxyz, float* __restrict__ out_inds_f) {
    __shared__ float smem[3 * N];                       // 48 KB transpose tile
    __shared__ __align__(16) unsigned long long skey[2][8];   // [parity][wave] winner key
    __shared__ __align__(16) float4 scoord[2][8];             // [parity][wave] winner coords
    __shared__ int lhist[NP];                           // FPS selection history (LDS only)
    int bid = blockIdx.x;
    int t = threadIdx.x;

    if (bid >= FPS_BLOCKS) {
        int hb = bid - FPS_BLOCKS;
        if (hb < TR_BLOCKS) {
            // ---- transpose feat (B,C,N) fp32 -> featT (B,N,256) bf16, 32x128 tile ----
            float* ls = smem;
            int b2 = hb >> 8, rem = hb & 255;
            int ct = rem >> 5, jt = rem & 31;
            int c0 = ct * 32, j0 = jt * 128;
            const float* src = feat + (size_t)b2 * C * N;
            #pragma unroll
            for (int i = 0; i < 8; i++) {
                int lin = t + 512 * i;
                int jj = lin & 127, cc = lin >> 7;
                ls[cc * 129 + jj] = src[(size_t)(c0 + cc) * N + j0 + jj];
            }
            __syncthreads();
            int c8 = t & 3, jj = t >> 2;
            unsigned pk[4];
            #pragma unroll
            for (int q = 0; q < 4; q++) {
                float f0 = ls[(c8 * 8 + 2 * q) * 129 + jj];
                float f1 = ls[(c8 * 8 + 2 * q + 1) * 129 + jj];
                pk[q] = (unsigned)f2bf(f0) | ((unsigned)f2bf(f1) << 16);
            }
            *(uint4*)&featT[((size_t)b2 * N + j0 + jj) * 256 + c0 + c8 * 8] =
                make_uint4(pk[0], pk[1], pk[2], pk[3]);
        } else {
            // ---- prep: weights -> bf16 [o][k]; zero stats ----
            int i0 = (hb - TR_BLOCKS) * 512 + t;
            if (i0 < 256 * HID) { int o = i0 >> 8, k = i0 & 255; w1fb[i0] = f2bf(w1[o * CIN + 3 + k]); }
            if (i0 < HID * HID) { w2b[i0] = f2bf(w2[i0]); w3b[i0] = f2bf(w3[i0]); }
            if (i0 < 3 * 512) stats[i0] = 0.f;
        }
        return;
    }

    // ---- FPS for batch b = bid: zero global memory ops inside the loop ----
    int b = bid;
    const float* sp = seed + (size_t)b * N * 3;
    float px[8], py[8], pz[8], dloc[8];
    #pragma unroll
    for (int u = 0; u < 8; u++) {
        int i = t + 512 * u;
        px[u] = sp[i * 3 + 0]; py[u] = sp[i * 3 + 1]; pz[u] = sp[i * 3 + 2];
        dloc[u] = 1e10f;
    }
    if (t == 0) lhist[0] = 0;
    float lx = sp[0], ly = sp[1], lz = sp[2];   // first selected point = index 0
    int lane = t & 63, w = t >> 6;
    for (int k = 1; k < NP; k++) {
        float bv = -1.f; int bi = 0;
        float bx = 0.f, by = 0.f, bz = 0.f;
        #pragma unroll
        for (int u = 0; u < 8; u++) {
            int i = t + 512 * u;
            float dx = __fsub_rn(px[u], lx);
            float dy = __fsub_rn(py[u], ly);
            float dz = __fsub_rn(pz[u], lz);
            float d  = __fadd_rn(__fadd_rn(__fmul_rn(dx, dx), __fmul_rn(dy, dy)), __fmul_rn(dz, dz));
            float dm = fminf(dloc[u], d);
            dloc[u] = dm;
            bool bt = dm > bv;            // i ascending in u -> strict > keeps min index
            bv = bt ? dm : bv;
            bi = bt ? i : bi;
            bx = bt ? px[u] : bx;
            by = bt ? py[u] : by;
            bz = bt ? pz[u] : bz;
        }
        // phase 1: wave max distance (nonneg f32 -> int compare valid), DPP
        int wm = wave_max_i32(__float_as_int(bv));
        // phase 2: min index among lanes holding the max (unsigned max of ~idx; losers 0)
        unsigned cand = (__float_as_int(bv) == wm) ? ~(unsigned)bi : 0u;
        unsigned winv = wave_max_u32(cand);
        int wbi = (int)(~winv);
        int par = k & 1;
        // winner lane (lane == wbi&63 uniquely holds point wbi) writes key + coords
        if (lane == (wbi & 63)) {
            skey[par][w] = (((unsigned long long)(unsigned)wm) << 12) | (unsigned)(4095 - wbi);
            scoord[par][w] = make_float4(bx, by, bz, 0.f);
        }
        __syncthreads();
        // cross-wave: read 8 keys as 4x b128, 3-level tree, then one broadcast coord read
        const ulonglong2* kp = (const ulonglong2*)&skey[par][0];
        ulonglong2 q0 = kp[0], q1 = kp[1], q2 = kp[2], q3 = kp[3];
        unsigned long long a = umax64(q0.x, q0.y);
        unsigned long long c2 = umax64(q1.x, q1.y);
        unsigned long long e = umax64(q2.x, q2.y);
        unsigned long long g = umax64(q3.x, q3.y);
        unsigned long long h = umax64(umax64(a, c2), umax64(e, g));
        int gi = 4095 - (int)(h & 0xFFFull);
        int ws = (gi & 511) >> 6;
        float4 wc = scoord[par][ws];
        lx = wc.x; ly = wc.y; lz = wc.z;
        if (t == 0) lhist[k] = gi;
    }
    __syncthreads();
    {
        int p = t;   // 512 threads cover NP=512
        int j = lhist[p];
        const float* xb = xyz + ((size_t)b * N + j) * 3;
        float* ob = out_newxyz + ((size_t)b * NP + p) * 3;
        ob[0] = xb[0]; ob[1] = xb[1]; ob[2] = xb[2];
        out_inds_f[b * NP + p] = (float)j;
    }
}

// ---------------- ball query: wave-parallel ballot scan, first NS by index ----------------
__global__ __launch_bounds__(256) void ballquery_kernel(const float* __restrict__ xyz,
        const float* __restrict__ newxyz, int* __restrict__ idx) {
    __shared__ float sx[N], sy[N], sz[N];
    int blk = blockIdx.x;
    int b   = blk >> 5;
    int q00 = (blk & 31) * 16;
    int t = threadIdx.x, lane = t & 63, w = t >> 6;
    const float* xb = xyz + (size_t)b * N * 3;
    for (int i = t; i < N; i += 256) { sx[i] = xb[i * 3]; sy[i] = xb[i * 3 + 1]; sz[i] = xb[i * 3 + 2]; }
    __syncthreads();
    for (int qi = 0; qi < 4; qi++) {
        int q = q00 + w * 4 + qi;
        const float* nq = newxyz + ((size_t)(b * NP + q)) * 3;
        float qx = nq[0], qy = nq[1], qz = nq[2];
        int* out = idx + ((size_t)(b * NP + q)) * NS;
        int cnt = 0, first = -1;
        for (int it = 0; it < 64; it++) {
            int j = it * 64 + lane;
            float dx = __fsub_rn(sx[j], qx);
            float dy = __fsub_rn(sy[j], qy);
            float dz = __fsub_rn(sz[j], qz);
            float d2 = __fadd_rn(__fadd_rn(__fmul_rn(dx, dx), __fmul_rn(dy, dy)), __fmul_rn(dz, dz));
            bool inb = d2 < 0.09f;
            unsigned long long m = __ballot(inb);
            if (m) {
                if (first < 0) first = it * 64 + __builtin_ctzll(m);
                if (inb) {
                    int r = cnt + __popcll(m & ((1ull << lane) - 1ull));
                    if (r < NS) out[r] = j;
                }
                cnt += __popcll(m);
                if (cnt >= NS) break;
            }
        }
        if (cnt < NS && lane >= cnt && lane < NS) out[lane] = first;
    }
}

// ---------------- GEMM1 (MFMA bf16): y1[s][o] = w1feat . gathered featT + xyz epilogue + fused stats ----------------
__global__ __launch_bounds__(256) void gemm1_mfma(
        const unsigned short* __restrict__ w1fb, const float* __restrict__ w1raw,
        const unsigned short* __restrict__ featT, const float* __restrict__ newxyz,
        const float* __restrict__ xyz, const int* __restrict__ idx,
        unsigned short* __restrict__ y1, float* __restrict__ statsOut) {
    __shared__ unsigned short Xs[128][136];       // [s][k] slab, reused as [s][o] out tile
    __shared__ float xn0[128], xn1[128], xn2[128];
    __shared__ int jl[128];
    int t = threadIdx.x;
    int s0 = blockIdx.x * 128;
    int b = s0 >> 13;
    if (t < 128) {
        int pn = (s0 & (SB - 1)) + t;
        int p = pn >> 4, n = pn & 15;
        int j = idx[((size_t)(b * NP + p)) * NS + n];
        jl[t] = j;
        const float* xb = xyz + ((size_t)(b * N + j)) * 3;
        const float* nq = newxyz + ((size_t)(b * NP + p)) * 3;
        xn0[t] = (xb[0] - nq[0]) / 0.3f;
        xn1[t] = (xb[1] - nq[1]) / 0.3f;
        xn2[t] = (xb[2] - nq[2]) / 0.3f;
    }
    __syncthreads();
    int lane = t & 63, w = t >> 6;
    int row16 = lane & 15, quad = lane >> 4;
    floatx4 acc[2][8];
    #pragma unroll
    for (int mt = 0; mt < 2; mt++)
        #pragma unroll
        for (int nt = 0; nt < 8; nt++)
            acc[mt][nt] = (floatx4){0.f, 0.f, 0.f, 0.f};
    int ss = t >> 1, hh = (t & 1) * 64;
    const unsigned short* grow = featT + ((size_t)b * N + jl[ss]) * 256 + hh;
    for (int slab = 0; slab < 2; slab++) {
        int k0 = slab * 128;
        {
            const uint4* src = (const uint4*)(grow + k0);
            #pragma unroll
            for (int i = 0; i < 8; i++)
                *(uint4*)&Xs[ss][hh + i * 8] = src[i];
        }
        __syncthreads();
        #pragma unroll
        for (int kk = 0; kk < 128; kk += 32) {
            short8 a0 = *(const short8*)&w1fb[(size_t)(w * 32 + row16) * 256 + k0 + kk + quad * 8];
            short8 a1 = *(const short8*)&w1fb[(size_t)(w * 32 + 16 + row16) * 256 + k0 + kk + quad * 8];
            #pragma unroll
            for (int nt = 0; nt < 8; nt++) {
                short8 bf = *(const short8*)&Xs[nt * 16 + row16][kk + quad * 8];
                acc[0][nt] = __builtin_amdgcn_mfma_f32_16x16x32_bf16(a0, bf, acc[0][nt], 0, 0, 0);
                acc[1][nt] = __builtin_amdgcn_mfma_f32_16x16x32_bf16(a1, bf, acc[1][nt], 0, 0, 0);
            }
        }
        __syncthreads();
    }
    // epilogue: + w1_xyz . xn (fp32), pack bf16, tile [s][o], coalesced global write + stats
    float wa[8], wbv[8], wc[8];
    #pragma unroll
    for (int mt = 0; mt < 2; mt++)
        #pragma unroll
        for (int r = 0; r < 4; r++) {
            int o = w * 32 + mt * 16 + quad * 4 + r;
            const float* wr = w1raw + (size_t)o * CIN;
            wa[mt * 4 + r] = wr[0]; wbv[mt * 4 + r] = wr[1]; wc[mt * 4 + r] = wr[2];
        }
    float x0l[8], x1l[8], x2l[8];
    #pragma unroll
    for (int nt = 0; nt < 8; nt++) {
        int s = nt * 16 + row16;
        x0l[nt] = xn0[s]; x1l[nt] = xn1[s]; x2l[nt] = xn2[s];
    }
    float s8[2][4] = {}, q8[2][4] = {};
    #pragma unroll
    for (int mt = 0; mt < 2; mt++)
        #pragma unroll
        for (int nt = 0; nt < 8; nt++) {
            int s = nt * 16 + row16;
            int ob = w * 32 + mt * 16 + quad * 4;
            floatx4 a = acc[mt][nt];
            float v0 = a[0] + wa[mt*4+0]*x0l[nt] + wbv[mt*4+0]*x1l[nt] + wc[mt*4+0]*x2l[nt];
            float v1 = a[1] + wa[mt*4+1]*x0l[nt] + wbv[mt*4+1]*x1l[nt] + wc[mt*4+1]*x2l[nt];
            float v2 = a[2] + wa[mt*4+2]*x0l[nt] + wbv[mt*4+2]*x1l[nt] + wc[mt*4+2]*x2l[nt];
            float v3 = a[3] + wa[mt*4+3]*x0l[nt] + wbv[mt*4+3]*x1l[nt] + wc[mt*4+3]*x2l[nt];
            s8[mt][0] += v0; q8[mt][0] = fmaf(v0, v0, q8[mt][0]);
            s8[mt][1] += v1; q8[mt][1] = fmaf(v1, v1, q8[mt][1]);
            s8[mt][2] += v2; q8[mt][2] = fmaf(v2, v2, q8[mt][2]);
            s8[mt][3] += v3; q8[mt][3] = fmaf(v3, v3, q8[mt][3]);
            unsigned p0 = (unsigned)f2bf(v0) | ((unsigned)f2bf(v1) << 16);
            unsigned p1 = (unsigned)f2bf(v2) | ((unsigned)f2bf(v3) << 16);
            *(uint2*)&Xs[s][ob] = make_uint2(p0, p1);
        }
    // per-channel stats: reduce over the 16-lane row (covers all 128 s within thread+row)
    #pragma unroll
    for (int mt = 0; mt < 2; mt++)
        #pragma unroll
        for (int r = 0; r < 4; r++) {
            float sv = row16_sum(s8[mt][r]);
            float qv = row16_sum(q8[mt][r]);
            if ((lane & 15) == 15) {
                int o = w * 32 + mt * 16 + quad * 4 + r;
                atomicAdd(&statsOut[o], sv);
                atomicAdd(&statsOut[128 + o], qv);
            }
        }
    __syncthreads();
    int c = t & 15, sr = t >> 4;
    #pragma unroll
    for (int i = 0; i < 8; i++) {
        int s = sr + 16 * i;
        uint4 v = *(const uint4*)&Xs[s][c * 8];
        *(uint4*)&y1[(size_t)(s0 + s) * 128 + c * 8] = v;
    }
}

// ---------------- GEMM2 (MFMA bf16): inline bnparam(prev) + X=relu(affine(yprev)), Y=W*X + fused stats ----------------
__global__ __launch_bounds__(256) void gemm_bn_mfma(
        const unsigned short* __restrict__ wb16, const unsigned short* __restrict__ yprev,
        const float* __restrict__ statsPrev, const float* __restrict__ gPrev,
        const float* __restrict__ bePrev, float* __restrict__ statsOut,
        unsigned short* __restrict__ yout) {
    __shared__ unsigned short Xs[128][136];
    __shared__ float ssc[128], ssh[128];
    int t = threadIdx.x;
    int s0 = blockIdx.x * 128;
    if (t < 128) {
        float mean = statsPrev[t] * (1.f / (float)S);
        float var  = statsPrev[128 + t] * (1.f / (float)S) - mean * mean;
        float sc = gPrev[t] / sqrtf(var + EPSF);
        ssc[t] = sc;
        ssh[t] = bePrev[t] - mean * sc;
    }
    __syncthreads();
    int ss = t >> 1, hh = (t & 1) * 64;
    {
        const uint4* src = (const uint4*)&yprev[(size_t)(s0 + ss) * 128 + hh];
        #pragma unroll
        for (int i = 0; i < 8; i++) {
            uint4 raw = src[i];
            int kb = hh + i * 8;
            float4 c0 = *(float4*)&ssc[kb];
            float4 c1 = *(float4*)&ssc[kb + 4];
            float4 h0 = *(float4*)&ssh[kb];
            float4 h1 = *(float4*)&ssh[kb + 4];
            float f0 = fmaxf(0.f, fmaf(bf2f((unsigned short)(raw.x & 0xFFFF)), c0.x, h0.x));
            float f1 = fmaxf(0.f, fmaf(bf2f((unsigned short)(raw.x >> 16)),    c0.y, h0.y));
            float f2 = fmaxf(0.f, fmaf(bf2f((unsigned short)(raw.y & 0xFFFF)), c0.z, h0.z));
            float f3 = fmaxf(0.f, fmaf(bf2f((unsigned short)(raw.y >> 16)),    c0.w, h0.w));
            float f4 = fmaxf(0.f, fmaf(bf2f((unsigned short)(raw.z & 0xFFFF)), c1.x, h1.x));
            float f5 = fmaxf(0.f, fmaf(bf2f((unsigned short)(raw.z >> 16)),    c1.y, h1.y));
            float f6 = fmaxf(0.f, fmaf(bf2f((unsigned short)(raw.w & 0xFFFF)), c1.z, h1.z));
            float f7 = fmaxf(0.f, fmaf(bf2f((unsigned short)(raw.w >> 16)),    c1.w, h1.w));
            unsigned o0 = (unsigned)f2bf(f0) | ((unsigned)f2bf(f1) << 16);
            unsigned o1 = (unsigned)f2bf(f2) | ((unsigned)f2bf(f3) << 16);
            unsigned o2 = (unsigned)f2bf(f4) | ((unsigned)f2bf(f5) << 16);
            unsigned o3 = (unsigned)f2bf(f6) | ((unsigned)f2bf(f7) << 16);
            *(uint4*)&Xs[ss][kb] = make_uint4(o0, o1, o2, o3);
        }
    }
    __syncthreads();
    int lane = t & 63, w = t >> 6;
    int row16 = lane & 15, quad = lane >> 4;
    floatx4 acc[2][8];
    #pragma unroll
    for (int mt = 0; mt < 2; mt++)
        #pragma unroll
        for (int nt = 0; nt < 8; nt++)
            acc[mt][nt] = (floatx4){0.f, 0.f, 0.f, 0.f};
    #pragma unroll
    for (int kk = 0; kk < 128; kk += 32) {
        short8 a0 = *(const short8*)&wb16[(size_t)(w * 32 + row16) * 128 + kk + quad * 8];
        short8 a1 = *(const short8*)&wb16[(size_t)(w * 32 + 16 + row16) * 128 + kk + quad * 8];
        #pragma unroll
        for (int nt = 0; nt < 8; nt++) {
            short8 bf = *(const short8*)&Xs[nt * 16 + row16][kk + quad * 8];
            acc[0][nt] = __builtin_amdgcn_mfma_f32_16x16x32_bf16(a0, bf, acc[0][nt], 0, 0, 0);
            acc[1][nt] = __builtin_amdgcn_mfma_f32_16x16x32_bf16(a1, bf, acc[1][nt], 0, 0, 0);
        }
    }
    __syncthreads();
    float s8[2][4] = {}, q8[2][4] = {};
    #pragma unroll
    for (int mt = 0; mt < 2; mt++)
        #pragma unroll
        for (int nt = 0; nt < 8; nt++) {
            int s = nt * 16 + row16;
            int ob = w * 32 + mt * 16 + quad * 4;
            floatx4 a = acc[mt][nt];
            s8[mt][0] += a[0]; q8[mt][0] = fmaf(a[0], a[0], q8[mt][0]);
            s8[mt][1] += a[1]; q8[mt][1] = fmaf(a[1], a[1], q8[mt][1]);
            s8[mt][2] += a[2]; q8[mt][2] = fmaf(a[2], a[2], q8[mt][2]);
            s8[mt][3] += a[3]; q8[mt][3] = fmaf(a[3], a[3], q8[mt][3]);
            unsigned p0 = (unsigned)f2bf(a[0]) | ((unsigned)f2bf(a[1]) << 16);
            unsigned p1 = (unsigned)f2bf(a[2]) | ((unsigned)f2bf(a[3]) << 16);
            *(uint2*)&Xs[s][ob] = make_uint2(p0, p1);
        }
    #pragma unroll
    for (int mt = 0; mt < 2; mt++)
        #pragma unroll
        for (int r = 0; r < 4; r++) {
            float sv = row16_sum(s8[mt][r]);
            float qv = row16_sum(q8[mt][r]);
            if ((lane & 15) == 15) {
                int o = w * 32 + mt * 16 + quad * 4 + r;
                atomicAdd(&statsOut[o], sv);
                atomicAdd(&statsOut[128 + o], qv);
            }
        }
    __syncthreads();
    int c = t & 15, sr = t >> 4;
    #pragma unroll
    for (int i = 0; i < 8; i++) {
        int s = sr + 16 * i;
        uint4 v = *(const uint4*)&Xs[s][c * 8];
        *(uint4*)&yout[(size_t)(s0 + s) * 128 + c * 8] = v;
    }
}

// ---------------- GEMM3: inline bnparam(2) + MFMA + fused stats3 + fused maxpool (raw fp32 max) ----------------
// NOTE: maxpool commutes with BN3-affine+relu because sc3 = g3/sqrt(var+eps) >= 0 (g3 = ones).
// y3 is never materialized; raw per-(p,o) maxima go directly into out_feat, finalized in place.
__global__ __launch_bounds__(256) void gemm3_pool_mfma(
        const unsigned short* __restrict__ wb16, const unsigned short* __restrict__ yprev,
        const float* __restrict__ statsPrev, const float* __restrict__ gPrev,
        const float* __restrict__ bePrev, float* __restrict__ statsOut,
        float* __restrict__ out_feat) {
    __shared__ unsigned short Xs[128][136];
    __shared__ float ssc[128], ssh[128];
    __shared__ float pool[8][133];
    int t = threadIdx.x;
    int s0 = blockIdx.x * 128;
    if (t < 128) {
        float mean = statsPrev[t] * (1.f / (float)S);
        float var  = statsPrev[128 + t] * (1.f / (float)S) - mean * mean;
        float sc = gPrev[t] / sqrtf(var + EPSF);
        ssc[t] = sc;
        ssh[t] = bePrev[t] - mean * sc;
    }
    __syncthreads();
    int ss = t >> 1, hh = (t & 1) * 64;
    {
        const uint4* src = (const uint4*)&yprev[(size_t)(s0 + ss) * 128 + hh];
        #pragma unroll
        for (int i = 0; i < 8; i++) {
            uint4 raw = src[i];
            int kb = hh + i * 8;
            float4 c0 = *(float4*)&ssc[kb];
            float4 c1 = *(float4*)&ssc[kb + 4];
            float4 h0 = *(float4*)&ssh[kb];
            float4 h1 = *(float4*)&ssh[kb + 4];
            float f0 = fmaxf(0.f, fmaf(bf2f((unsigned short)(raw.x & 0xFFFF)), c0.x, h0.x));
            float f1 = fmaxf(0.f, fmaf(bf2f((unsigned short)(raw.x >> 16)),    c0.y, h0.y));
            float f2 = fmaxf(0.f, fmaf(bf2f((unsigned short)(raw.y & 0xFFFF)), c0.z, h0.z));
            float f3 = fmaxf(0.f, fmaf(bf2f((unsigned short)(raw.y >> 16)),    c0.w, h0.w));
            float f4 = fmaxf(0.f, fmaf(bf2f((unsigned short)(raw.z & 0xFFFF)), c1.x, h1.x));
            float f5 = fmaxf(0.f, fmaf(bf2f((unsigned short)(raw.z >> 16)),    c1.y, h1.y));
            float f6 = fmaxf(0.f, fmaf(bf2f((unsigned short)(raw.w & 0xFFFF)), c1.z, h1.z));
            float f7 = fmaxf(0.f, fmaf(bf2f((unsigned short)(raw.w >> 16)),    c1.w, h1.w));
            unsigned o0 = (unsigned)f2bf(f0) | ((unsigned)f2bf(f1) << 16);
            unsigned o1 = (unsigned)f2bf(f2) | ((unsigned)f2bf(f3) << 16);
            unsigned o2 = (unsigned)f2bf(f4) | ((unsigned)f2bf(f5) << 16);
            unsigned o3 = (unsigned)f2bf(f6) | ((unsigned)f2bf(f7) << 16);
            *(uint4*)&Xs[ss][kb] = make_uint4(o0, o1, o2, o3);
        }
    }
    __syncthreads();
    int lane = t & 63, w = t >> 6;
    int row16 = lane & 15, quad = lane >> 4;
    floatx4 acc[2][8];
    #pragma unroll
    for (int mt = 0; mt < 2; mt++)
        #pragma unroll
        for (int nt = 0; nt < 8; nt++)
            acc[mt][nt] = (floatx4){0.f, 0.f, 0.f, 0.f};
    #pragma unroll
    for (int kk = 0; kk < 128; kk += 32) {
        short8 a0 = *(const short8*)&wb16[(size_t)(w * 32 + row16) * 128 + kk + quad * 8];
        short8 a1 = *(const short8*)&wb16[(size_t)(w * 32 + 16 + row16) * 128 + kk + quad * 8];
        #pragma unroll
        for (int nt = 0; nt < 8; nt++) {
            short8 bf = *(const short8*)&Xs[nt * 16 + row16][kk + quad * 8];
            acc[0][nt] = __builtin_amdgcn_mfma_f32_16x16x32_bf16(a0, bf, acc[0][nt], 0, 0, 0);
            acc[1][nt] = __builtin_amdgcn_mfma_f32_16x16x32_bf16(a1, bf, acc[1][nt], 0, 0, 0);
        }
    }
    // columns: s = nt*16 + row16 -> pool p_local = nt, pool lane n = row16
    float s8[2][4] = {}, q8[2][4] = {};
    #pragma unroll
    for (int mt = 0; mt < 2; mt++)
        #pragma unroll
        for (int nt = 0; nt < 8; nt++) {
            floatx4 a = acc[mt][nt];
            #pragma unroll
            for (int r = 0; r < 4; r++) {
                float v = a[r];
                s8[mt][r] += v;
                q8[mt][r] = fmaf(v, v, q8[mt][r]);
                float mx = row16_max(v);
                if ((lane & 15) == 15)
                    pool[nt][w * 32 + mt * 16 + quad * 4 + r] = mx;
            }
        }
    #pragma unroll
    for (int mt = 0; mt < 2; mt++)
        #pragma unroll
        for (int r = 0; r < 4; r++) {
            float sv = row16_sum(s8[mt][r]);
            float qv = row16_sum(q8[mt][r]);
            if ((lane & 15) == 15) {
                int o = w * 32 + mt * 16 + quad * 4 + r;
                atomicAdd(&statsOut[o], sv);
                atomicAdd(&statsOut[128 + o], qv);
            }
        }
    __syncthreads();
    // store raw maxima: out_feat[b][o][p]
    {
        int b = s0 >> 13;
        int pcol0 = (s0 & (SB - 1)) >> 4;
        int o = t >> 1, half = (t & 1) * 4;
        float4 v = make_float4(pool[half + 0][o], pool[half + 1][o],
                               pool[half + 2][o], pool[half + 3][o]);
        *(float4*)&out_feat[((size_t)b * HID + o) * NP + pcol0 + half] = v;
    }
}

// ---------------- finalize: in-place BN3 affine + relu on pooled raw maxima ----------------
__global__ __launch_bounds__(256) void finalize_kernel(float* __restrict__ out_feat,
        const float* __restrict__ st3, const float* __restrict__ g,
        const float* __restrict__ be) {
    int i = (blockIdx.x * 256 + threadIdx.x) * 4;   // over B*HID*NP = 2M floats
    int o = (i >> 9) & 127;                          // layout (B,HID,NP), NP=512
    float mean = st3[o] * (1.f / (float)S);
    float var  = st3[128 + o] * (1.f / (float)S) - mean * mean;
    float sc = g[o] / sqrtf(var + EPSF);
    float sh = be[o] - mean * sc;
    float4 v = *(float4*)&out_feat[i];
    v.x = fmaxf(0.f, fmaf(v.x, sc, sh));
    v.y = fmaxf(0.f, fmaf(v.y, sc, sh));
    v.z = fmaxf(0.f, fmaf(v.z, sc, sh));
    v.w = fmaxf(0.f, fmaf(v.w, sc, sh));
    *(float4*)&out_feat[i] = v;
}

extern "C" void kernel_launch(void* const* d_in, const int* in_sizes, int n_in,
                              void* d_out, int out_size, void* d_ws, size_t ws_size,
                              hipStream_t stream) {
    const float* xyz  = (const float*)d_in[0];
    const float* feat = (const float*)d_in[1];
    const float* seed = (const float*)d_in[2];
    const float* w1 = (const float*)d_in[3];
    const float* g1 = (const float*)d_in[4];
    const float* be1 = (const float*)d_in[5];
    const float* w2 = (const float*)d_in[6];
    const float* g2 = (const float*)d_in[7];
    const float* be2 = (const float*)d_in[8];
    const float* w3 = (const float*)d_in[9];
    const float* g3 = (const float*)d_in[10];
    const float* be3 = (const float*)d_in[11];

    float* out_newxyz = (float*)d_out;                 // (B,NP,3)
    float* out_feat   = out_newxyz + B * NP * 3;       // (B,HID,NP)
    float* out_inds   = out_feat + B * HID * NP;       // (B,NP) as float

    float* stats = (float*)d_ws;                       // 3 layers x [sum(128)|sq(128)] (256-stride)
    int*   inds  = (int*)(stats + 3 * 512);
    int*   idx   = inds + B * NP;
    unsigned short* w1fb  = (unsigned short*)(idx + (size_t)B * NP * NS);
    unsigned short* w2b   = w1fb + 256 * HID;
    unsigned short* w3b   = w2b + HID * HID;
    unsigned short* featT = w3b + HID * HID;           // B*N*256 bf16
    unsigned short* y1    = featT + (size_t)B * N * 256;   // S*128 bf16
    unsigned short* y2    = featT;                     // alias: featT dead after gemm1

    size_t need = (size_t)(3 * 512) * 4 + (size_t)B * NP * 4 + (size_t)B * NP * NS * 4
                + (size_t)(256 * HID + 2 * HID * HID) * 2
                + 2ull * (size_t)B * N * 256 * 2;
    if (ws_size < need) return;

    fused_front_kernel<<<FPS_BLOCKS + TR_BLOCKS + PREP_BLOCKS, 512, 0, stream>>>(
        seed, xyz, feat, w1, w2, w3, featT, w1fb, w2b, w3b, stats,
        inds, out_newxyz, out_inds);
    ballquery_kernel<<<B * 32, 256, 0, stream>>>(xyz, out_newxyz, idx);
    gemm1_mfma<<<S / 128, 256, 0, stream>>>(w1fb, w1, featT, out_newxyz, xyz, idx, y1, stats);
    gemm_bn_mfma<<<S / 128, 256, 0, stream>>>(w2b, y1, stats, g1, be1, stats + 256, y2);
    gemm3_pool_mfma<<<S / 128, 256, 0, stream>>>(w3b, y2, stats + 256, g2, be2, stats + 512, out_feat);
    finalize_kernel<<<(B * HID * NP) / 1024, 256, 0, stream>>>(out_feat, stats + 512, g3, be3);
}

// Round 4
// 739.956 us; speedup vs baseline: 1.6727x; 1.6727x over previous
//
#include <hip/hip_runtime.h>
#include <cstdint>
#include <cstddef>

#define B   32
#define N   4096
#define NP  512
#define NS  16
#define C   256
#define CIN 259
#define HID 128
#define SB  (NP*NS)      // 8192 columns per batch
#define S   (B*SB)       // 262144 total columns
#define EPSF 1e-5f

#define FPS_BLOCKS 32
#define TR_BLOCKS  (B*256)   // 8192 transpose tiles
#define PREP_BLOCKS 64

#define NREP 32              // stats replicas (atomic chain depth = blocks/NREP = 64)
#define LSTRIDE (NREP*256)   // floats per stats layer

typedef __attribute__((ext_vector_type(8))) short short8;
typedef __attribute__((ext_vector_type(4))) float floatx4;

__device__ __forceinline__ float bf2f(unsigned short u) {
    return __uint_as_float(((unsigned)u) << 16);
}
__device__ __forceinline__ unsigned short f2bf(float f) {
    unsigned u = __float_as_uint(f);
    return (unsigned short)((u + 0x7FFFu + ((u >> 16) & 1u)) >> 16);
}

// wave64 max of nonneg-float bits via DPP (VALU pipe, no LDS crossbar), result uniform
__device__ __forceinline__ int wave_max_i32(int x) {
    int y;
    y = __builtin_amdgcn_update_dpp(0, x, 0x111, 0xf, 0xf, true); x = (y > x) ? y : x;
    y = __builtin_amdgcn_update_dpp(0, x, 0x112, 0xf, 0xf, true); x = (y > x) ? y : x;
    y = __builtin_amdgcn_update_dpp(0, x, 0x114, 0xf, 0xf, true); x = (y > x) ? y : x;
    y = __builtin_amdgcn_update_dpp(0, x, 0x118, 0xf, 0xf, true); x = (y > x) ? y : x;
    y = __builtin_amdgcn_update_dpp(0, x, 0x142, 0xa, 0xf, true); x = (y > x) ? y : x;
    y = __builtin_amdgcn_update_dpp(0, x, 0x143, 0xc, 0xf, true); x = (y > x) ? y : x;
    return __builtin_amdgcn_readlane(x, 63);
}
__device__ __forceinline__ unsigned wave_max_u32(unsigned x) {
    unsigned y;
    y = (unsigned)__builtin_amdgcn_update_dpp(0, (int)x, 0x111, 0xf, 0xf, true); x = (y > x) ? y : x;
    y = (unsigned)__builtin_amdgcn_update_dpp(0, (int)x, 0x112, 0xf, 0xf, true); x = (y > x) ? y : x;
    y = (unsigned)__builtin_amdgcn_update_dpp(0, (int)x, 0x114, 0xf, 0xf, true); x = (y > x) ? y : x;
    y = (unsigned)__builtin_amdgcn_update_dpp(0, (int)x, 0x118, 0xf, 0xf, true); x = (y > x) ? y : x;
    y = (unsigned)__builtin_amdgcn_update_dpp(0, (int)x, 0x142, 0xa, 0xf, true); x = (y > x) ? y : x;
    y = (unsigned)__builtin_amdgcn_update_dpp(0, (int)x, 0x143, 0xc, 0xf, true); x = (y > x) ? y : x;
    return (unsigned)__builtin_amdgcn_readlane((int)x, 63);
}

__device__ __forceinline__ unsigned long long umax64(unsigned long long a, unsigned long long b) {
    return (b > a) ? b : a;
}

// sum over each 16-lane row; lanes with (lane&15)==15 hold the full row sum
__device__ __forceinline__ float row16_sum(float x) {
    float y;
    y = __int_as_float(__builtin_amdgcn_update_dpp(0, __float_as_int(x), 0x111, 0xf, 0xf, true)); x += y;
    y = __int_as_float(__builtin_amdgcn_update_dpp(0, __float_as_int(x), 0x112, 0xf, 0xf, true)); x += y;
    y = __int_as_float(__builtin_amdgcn_update_dpp(0, __float_as_int(x), 0x114, 0xf, 0xf, true)); x += y;
    y = __int_as_float(__builtin_amdgcn_update_dpp(0, __float_as_int(x), 0x118, 0xf, 0xf, true)); x += y;
    return x;
}
// max over each 16-lane row (invalid lanes keep old value); lane&15==15 holds row max
__device__ __forceinline__ float row16_max(float x) {
    int xi = __float_as_int(x);
    float y;
    y = __int_as_float(__builtin_amdgcn_update_dpp(xi, xi, 0x111, 0xf, 0xf, false)); x = fmaxf(x, y); xi = __float_as_int(x);
    y = __int_as_float(__builtin_amdgcn_update_dpp(xi, xi, 0x112, 0xf, 0xf, false)); x = fmaxf(x, y); xi = __float_as_int(x);
    y = __int_as_float(__builtin_amdgcn_update_dpp(xi, xi, 0x114, 0xf, 0xf, false)); x = fmaxf(x, y); xi = __float_as_int(x);
    y = __int_as_float(__builtin_amdgcn_update_dpp(xi, xi, 0x118, 0xf, 0xf, false)); x = fmaxf(x, y);
    return x;
}

// ---------------- fused front: FPS + feat transpose(bf16) + weight prep(bf16) ----------------
__global__ __launch_bounds__(512) void fused_front_kernel(
        const float* __restrict__ seed, const float* __restrict__ xyz,
        const float* __restrict__ feat, const float* __restrict__ w1,
        const float* __restrict__ w2, const float* __restrict__ w3,
        unsigned short* __restrict__ featT, unsigned short* __restrict__ w1fb,
        unsigned short* __restrict__ w2b, unsigned short* __restrict__ w3b,
        float* __restrict__ stats, int* __restrict__ inds,
        float* __restrict__ out_newxyz, float* __restrict__ out_inds_f) {
    __shared__ float smem[3 * N];                       // 48 KB transpose tile
    __shared__ __align__(16) unsigned long long skey[2][8];   // [parity][wave] winner key
    __shared__ __align__(16) float4 scoord[2][8];             // [parity][wave] winner coords
    __shared__ int lhist[NP];                           // FPS selection history (LDS only)
    int bid = blockIdx.x;
    int t = threadIdx.x;

    if (bid >= FPS_BLOCKS) {
        int hb = bid - FPS_BLOCKS;
        if (hb < TR_BLOCKS) {
            // ---- transpose feat (B,C,N) fp32 -> featT (B,N,256) bf16, 32x128 tile ----
            float* ls = smem;
            int b2 = hb >> 8, rem = hb & 255;
            int ct = rem >> 5, jt = rem & 31;
            int c0 = ct * 32, j0 = jt * 128;
            const float* src = feat + (size_t)b2 * C * N;
            #pragma unroll
            for (int i = 0; i < 8; i++) {
                int lin = t + 512 * i;
                int jj = lin & 127, cc = lin >> 7;
                ls[cc * 129 + jj] = src[(size_t)(c0 + cc) * N + j0 + jj];
            }
            __syncthreads();
            int c8 = t & 3, jj = t >> 2;
            unsigned pk[4];
            #pragma unroll
            for (int q = 0; q < 4; q++) {
                float f0 = ls[(c8 * 8 + 2 * q) * 129 + jj];
                float f1 = ls[(c8 * 8 + 2 * q + 1) * 129 + jj];
                pk[q] = (unsigned)f2bf(f0) | ((unsigned)f2bf(f1) << 16);
            }
            *(uint4*)&featT[((size_t)b2 * N + j0 + jj) * 256 + c0 + c8 * 8] =
                make_uint4(pk[0], pk[1], pk[2], pk[3]);
        } else {
            // ---- prep: weights -> bf16 [o][k]; zero stats (3 layers x NREP x 256) ----
            int i0 = (hb - TR_BLOCKS) * 512 + t;
            if (i0 < 256 * HID) { int o = i0 >> 8, k = i0 & 255; w1fb[i0] = f2bf(w1[o * CIN + 3 + k]); }
            if (i0 < HID * HID) { w2b[i0] = f2bf(w2[i0]); w3b[i0] = f2bf(w3[i0]); }
            if (i0 < 3 * LSTRIDE) stats[i0] = 0.f;
        }
        return;
    }

    // ---- FPS for batch b = bid: zero global memory ops inside the loop ----
    int b = bid;
    const float* sp = seed + (size_t)b * N * 3;
    float px[8], py[8], pz[8], dloc[8];
    #pragma unroll
    for (int u = 0; u < 8; u++) {
        int i = t + 512 * u;
        px[u] = sp[i * 3 + 0]; py[u] = sp[i * 3 + 1]; pz[u] = sp[i * 3 + 2];
        dloc[u] = 1e10f;
    }
    if (t == 0) lhist[0] = 0;
    float lx = sp[0], ly = sp[1], lz = sp[2];   // first selected point = index 0
    int lane = t & 63, w = t >> 6;
    for (int k = 1; k < NP; k++) {
        float bv = -1.f; int bi = 0;
        float bx = 0.f, by = 0.f, bz = 0.f;
        #pragma unroll
        for (int u = 0; u < 8; u++) {
            int i = t + 512 * u;
            float dx = __fsub_rn(px[u], lx);
            float dy = __fsub_rn(py[u], ly);
            float dz = __fsub_rn(pz[u], lz);
            float d  = __fadd_rn(__fadd_rn(__fmul_rn(dx, dx), __fmul_rn(dy, dy)), __fmul_rn(dz, dz));
            float dm = fminf(dloc[u], d);
            dloc[u] = dm;
            bool bt = dm > bv;            // i ascending in u -> strict > keeps min index
            bv = bt ? dm : bv;
            bi = bt ? i : bi;
            bx = bt ? px[u] : bx;
            by = bt ? py[u] : by;
            bz = bt ? pz[u] : bz;
        }
        // phase 1: wave max distance (nonneg f32 -> int compare valid), DPP
        int wm = wave_max_i32(__float_as_int(bv));
        // phase 2: min index among lanes holding the max (unsigned max of ~idx; losers 0)
        unsigned cand = (__float_as_int(bv) == wm) ? ~(unsigned)bi : 0u;
        unsigned winv = wave_max_u32(cand);
        int wbi = (int)(~winv);
        int par = k & 1;
        // winner lane (lane == wbi&63 uniquely holds point wbi) writes key + coords
        if (lane == (wbi & 63)) {
            skey[par][w] = (((unsigned long long)(unsigned)wm) << 12) | (unsigned)(4095 - wbi);
            scoord[par][w] = make_float4(bx, by, bz, 0.f);
        }
        __syncthreads();
        // cross-wave: read 8 keys as 4x b128, 3-level tree, then one broadcast coord read
        const ulonglong2* kp = (const ulonglong2*)&skey[par][0];
        ulonglong2 q0 = kp[0], q1 = kp[1], q2 = kp[2], q3 = kp[3];
        unsigned long long a = umax64(q0.x, q0.y);
        unsigned long long c2 = umax64(q1.x, q1.y);
        unsigned long long e = umax64(q2.x, q2.y);
        unsigned long long g = umax64(q3.x, q3.y);
        unsigned long long h = umax64(umax64(a, c2), umax64(e, g));
        int gi = 4095 - (int)(h & 0xFFFull);
        int ws = (gi & 511) >> 6;
        float4 wc = scoord[par][ws];
        lx = wc.x; ly = wc.y; lz = wc.z;
        if (t == 0) lhist[k] = gi;
    }
    __syncthreads();
    {
        int p = t;   // 512 threads cover NP=512
        int j = lhist[p];
        const float* xb = xyz + ((size_t)b * N + j) * 3;
        float* ob = out_newxyz + ((size_t)b * NP + p) * 3;
        ob[0] = xb[0]; ob[1] = xb[1]; ob[2] = xb[2];
        out_inds_f[b * NP + p] = (float)j;
    }
}

// ---------------- ball query: wave-parallel ballot scan, first NS by index ----------------
__global__ __launch_bounds__(256) void ballquery_kernel(const float* __restrict__ xyz,
        const float* __restrict__ newxyz, int* __restrict__ idx) {
    __shared__ float sx[N], sy[N], sz[N];
    int blk = blockIdx.x;
    int b   = blk >> 5;
    int q00 = (blk & 31) * 16;
    int t = threadIdx.x, lane = t & 63, w = t >> 6;
    const float* xb = xyz + (size_t)b * N * 3;
    for (int i = t; i < N; i += 256) { sx[i] = xb[i * 3]; sy[i] = xb[i * 3 + 1]; sz[i] = xb[i * 3 + 2]; }
    __syncthreads();
    for (int qi = 0; qi < 4; qi++) {
        int q = q00 + w * 4 + qi;
        const float* nq = newxyz + ((size_t)(b * NP + q)) * 3;
        float qx = nq[0], qy = nq[1], qz = nq[2];
        int* out = idx + ((size_t)(b * NP + q)) * NS;
        int cnt = 0, first = -1;
        for (int it = 0; it < 64; it++) {
            int j = it * 64 + lane;
            float dx = __fsub_rn(sx[j], qx);
            float dy = __fsub_rn(sy[j], qy);
            float dz = __fsub_rn(sz[j], qz);
            float d2 = __fadd_rn(__fadd_rn(__fmul_rn(dx, dx), __fmul_rn(dy, dy)), __fmul_rn(dz, dz));
            bool inb = d2 < 0.09f;
            unsigned long long m = __ballot(inb);
            if (m) {
                if (first < 0) first = it * 64 + __builtin_ctzll(m);
                if (inb) {
                    int r = cnt + __popcll(m & ((1ull << lane) - 1ull));
                    if (r < NS) out[r] = j;
                }
                cnt += __popcll(m);
                if (cnt >= NS) break;
            }
        }
        if (cnt < NS && lane >= cnt && lane < NS) out[lane] = first;
    }
}

// ---------------- GEMM1 (MFMA bf16): y1[s][o] = w1feat . gathered featT + xyz epilogue + fused stats ----------------
__global__ __launch_bounds__(256) void gemm1_mfma(
        const unsigned short* __restrict__ w1fb, const float* __restrict__ w1raw,
        const unsigned short* __restrict__ featT, const float* __restrict__ newxyz,
        const float* __restrict__ xyz, const int* __restrict__ idx,
        unsigned short* __restrict__ y1, float* __restrict__ statsOut) {
    __shared__ unsigned short Xs[128][136];       // [s][k] slab, reused as [s][o] out tile
    __shared__ float xn0[128], xn1[128], xn2[128];
    __shared__ int jl[128];
    int t = threadIdx.x;
    int s0 = blockIdx.x * 128;
    int b = s0 >> 13;
    if (t < 128) {
        int pn = (s0 & (SB - 1)) + t;
        int p = pn >> 4, n = pn & 15;
        int j = idx[((size_t)(b * NP + p)) * NS + n];
        jl[t] = j;
        const float* xb = xyz + ((size_t)(b * N + j)) * 3;
        const float* nq = newxyz + ((size_t)(b * NP + p)) * 3;
        xn0[t] = (xb[0] - nq[0]) / 0.3f;
        xn1[t] = (xb[1] - nq[1]) / 0.3f;
        xn2[t] = (xb[2] - nq[2]) / 0.3f;
    }
    __syncthreads();
    int lane = t & 63, w = t >> 6;
    int row16 = lane & 15, quad = lane >> 4;
    floatx4 acc[2][8];
    #pragma unroll
    for (int mt = 0; mt < 2; mt++)
        #pragma unroll
        for (int nt = 0; nt < 8; nt++)
            acc[mt][nt] = (floatx4){0.f, 0.f, 0.f, 0.f};
    int ss = t >> 1, hh = (t & 1) * 64;
    const unsigned short* grow = featT + ((size_t)b * N + jl[ss]) * 256 + hh;
    for (int slab = 0; slab < 2; slab++) {
        int k0 = slab * 128;
        {
            const uint4* src = (const uint4*)(grow + k0);
            #pragma unroll
            for (int i = 0; i < 8; i++)
                *(uint4*)&Xs[ss][hh + i * 8] = src[i];
        }
        __syncthreads();
        #pragma unroll
        for (int kk = 0; kk < 128; kk += 32) {
            short8 a0 = *(const short8*)&w1fb[(size_t)(w * 32 + row16) * 256 + k0 + kk + quad * 8];
            short8 a1 = *(const short8*)&w1fb[(size_t)(w * 32 + 16 + row16) * 256 + k0 + kk + quad * 8];
            #pragma unroll
            for (int nt = 0; nt < 8; nt++) {
                short8 bf = *(const short8*)&Xs[nt * 16 + row16][kk + quad * 8];
                acc[0][nt] = __builtin_amdgcn_mfma_f32_16x16x32_bf16(a0, bf, acc[0][nt], 0, 0, 0);
                acc[1][nt] = __builtin_amdgcn_mfma_f32_16x16x32_bf16(a1, bf, acc[1][nt], 0, 0, 0);
            }
        }
        __syncthreads();
    }
    // epilogue: + w1_xyz . xn (fp32), pack bf16, tile [s][o], coalesced global write + stats
    float wa[8], wbv[8], wc[8];
    #pragma unroll
    for (int mt = 0; mt < 2; mt++)
        #pragma unroll
        for (int r = 0; r < 4; r++) {
            int o = w * 32 + mt * 16 + quad * 4 + r;
            const float* wr = w1raw + (size_t)o * CIN;
            wa[mt * 4 + r] = wr[0]; wbv[mt * 4 + r] = wr[1]; wc[mt * 4 + r] = wr[2];
        }
    float x0l[8], x1l[8], x2l[8];
    #pragma unroll
    for (int nt = 0; nt < 8; nt++) {
        int s = nt * 16 + row16;
        x0l[nt] = xn0[s]; x1l[nt] = xn1[s]; x2l[nt] = xn2[s];
    }
    float s8[2][4] = {}, q8[2][4] = {};
    #pragma unroll
    for (int mt = 0; mt < 2; mt++)
        #pragma unroll
        for (int nt = 0; nt < 8; nt++) {
            int s = nt * 16 + row16;
            int ob = w * 32 + mt * 16 + quad * 4;
            floatx4 a = acc[mt][nt];
            float v0 = a[0] + wa[mt*4+0]*x0l[nt] + wbv[mt*4+0]*x1l[nt] + wc[mt*4+0]*x2l[nt];
            float v1 = a[1] + wa[mt*4+1]*x0l[nt] + wbv[mt*4+1]*x1l[nt] + wc[mt*4+1]*x2l[nt];
            float v2 = a[2] + wa[mt*4+2]*x0l[nt] + wbv[mt*4+2]*x1l[nt] + wc[mt*4+2]*x2l[nt];
            float v3 = a[3] + wa[mt*4+3]*x0l[nt] + wbv[mt*4+3]*x1l[nt] + wc[mt*4+3]*x2l[nt];
            s8[mt][0] += v0; q8[mt][0] = fmaf(v0, v0, q8[mt][0]);
            s8[mt][1] += v1; q8[mt][1] = fmaf(v1, v1, q8[mt][1]);
            s8[mt][2] += v2; q8[mt][2] = fmaf(v2, v2, q8[mt][2]);
            s8[mt][3] += v3; q8[mt][3] = fmaf(v3, v3, q8[mt][3]);
            unsigned p0 = (unsigned)f2bf(v0) | ((unsigned)f2bf(v1) << 16);
            unsigned p1 = (unsigned)f2bf(v2) | ((unsigned)f2bf(v3) << 16);
            *(uint2*)&Xs[s][ob] = make_uint2(p0, p1);
        }
    // per-channel stats into replica slot (chain depth = blocks/NREP)
    {
        int rep = (blockIdx.x & (NREP - 1)) * 256;
        #pragma unroll
        for (int mt = 0; mt < 2; mt++)
            #pragma unroll
            for (int r = 0; r < 4; r++) {
                float sv = row16_sum(s8[mt][r]);
                float qv = row16_sum(q8[mt][r]);
                if ((lane & 15) == 15) {
                    int o = w * 32 + mt * 16 + quad * 4 + r;
                    atomicAdd(&statsOut[rep + o], sv);
                    atomicAdd(&statsOut[rep + 128 + o], qv);
                }
            }
    }
    __syncthreads();
    int c = t & 15, sr = t >> 4;
    #pragma unroll
    for (int i = 0; i < 8; i++) {
        int s = sr + 16 * i;
        uint4 v = *(const uint4*)&Xs[s][c * 8];
        *(uint4*)&y1[(size_t)(s0 + s) * 128 + c * 8] = v;
    }
}

// ---------------- GEMM2 (MFMA bf16): fold replicas + bnparam + X=relu(affine(yprev)), Y=W*X + fused stats ----------------
__global__ __launch_bounds__(256) void gemm_bn_mfma(
        const unsigned short* __restrict__ wb16, const unsigned short* __restrict__ yprev,
        const float* __restrict__ statsPrev, const float* __restrict__ gPrev,
        const float* __restrict__ bePrev, float* __restrict__ statsOut,
        unsigned short* __restrict__ yout) {
    __shared__ unsigned short Xs[128][136];
    __shared__ float ssc[128], ssh[128];
    int t = threadIdx.x;
    int s0 = blockIdx.x * 128;
    if (t < 128) {
        float sA = 0.f, qA = 0.f;
        #pragma unroll
        for (int r = 0; r < NREP; r++) {
            sA += statsPrev[r * 256 + t];
            qA += statsPrev[r * 256 + 128 + t];
        }
        float mean = sA * (1.f / (float)S);
        float var  = qA * (1.f / (float)S) - mean * mean;
        float sc = gPrev[t] / sqrtf(var + EPSF);
        ssc[t] = sc;
        ssh[t] = bePrev[t] - mean * sc;
    }
    __syncthreads();
    int ss = t >> 1, hh = (t & 1) * 64;
    {
        const uint4* src = (const uint4*)&yprev[(size_t)(s0 + ss) * 128 + hh];
        #pragma unroll
        for (int i = 0; i < 8; i++) {
            uint4 raw = src[i];
            int kb = hh + i * 8;
            float4 c0 = *(float4*)&ssc[kb];
            float4 c1 = *(float4*)&ssc[kb + 4];
            float4 h0 = *(float4*)&ssh[kb];
            float4 h1 = *(float4*)&ssh[kb + 4];
            float f0 = fmaxf(0.f, fmaf(bf2f((unsigned short)(raw.x & 0xFFFF)), c0.x, h0.x));
            float f1 = fmaxf(0.f, fmaf(bf2f((unsigned short)(raw.x >> 16)),    c0.y, h0.y));
            float f2 = fmaxf(0.f, fmaf(bf2f((unsigned short)(raw.y & 0xFFFF)), c0.z, h0.z));
            float f3 = fmaxf(0.f, fmaf(bf2f((unsigned short)(raw.y >> 16)),    c0.w, h0.w));
            float f4 = fmaxf(0.f, fmaf(bf2f((unsigned short)(raw.z & 0xFFFF)), c1.x, h1.x));
            float f5 = fmaxf(0.f, fmaf(bf2f((unsigned short)(raw.z >> 16)),    c1.y, h1.y));
            float f6 = fmaxf(0.f, fmaf(bf2f((unsigned short)(raw.w & 0xFFFF)), c1.z, h1.z));
            float f7 = fmaxf(0.f, fmaf(bf2f((unsigned short)(raw.w >> 16)),    c1.w, h1.w));
            unsigned o0 = (unsigned)f2bf(f0) | ((unsigned)f2bf(f1) << 16);
            unsigned o1 = (unsigned)f2bf(f2) | ((unsigned)f2bf(f3) << 16);
            unsigned o2 = (unsigned)f2bf(f4) | ((unsigned)f2bf(f5) << 16);
            unsigned o3 = (unsigned)f2bf(f6) | ((unsigned)f2bf(f7) << 16);
            *(uint4*)&Xs[ss][kb] = make_uint4(o0, o1, o2, o3);
        }
    }
    __syncthreads();
    int lane = t & 63, w = t >> 6;
    int row16 = lane & 15, quad = lane >> 4;
    floatx4 acc[2][8];
    #pragma unroll
    for (int mt = 0; mt < 2; mt++)
        #pragma unroll
        for (int nt = 0; nt < 8; nt++)
            acc[mt][nt] = (floatx4){0.f, 0.f, 0.f, 0.f};
    #pragma unroll
    for (int kk = 0; kk < 128; kk += 32) {
        short8 a0 = *(const short8*)&wb16[(size_t)(w * 32 + row16) * 128 + kk + quad * 8];
        short8 a1 = *(const short8*)&wb16[(size_t)(w * 32 + 16 + row16) * 128 + kk + quad * 8];
        #pragma unroll
        for (int nt = 0; nt < 8; nt++) {
            short8 bf = *(const short8*)&Xs[nt * 16 + row16][kk + quad * 8];
            acc[0][nt] = __builtin_amdgcn_mfma_f32_16x16x32_bf16(a0, bf, acc[0][nt], 0, 0, 0);
            acc[1][nt] = __builtin_amdgcn_mfma_f32_16x16x32_bf16(a1, bf, acc[1][nt], 0, 0, 0);
        }
    }
    __syncthreads();
    float s8[2][4] = {}, q8[2][4] = {};
    #pragma unroll
    for (int mt = 0; mt < 2; mt++)
        #pragma unroll
        for (int nt = 0; nt < 8; nt++) {
            int s = nt * 16 + row16;
            int ob = w * 32 + mt * 16 + quad * 4;
            floatx4 a = acc[mt][nt];
            s8[mt][0] += a[0]; q8[mt][0] = fmaf(a[0], a[0], q8[mt][0]);
            s8[mt][1] += a[1]; q8[mt][1] = fmaf(a[1], a[1], q8[mt][1]);
            s8[mt][2] += a[2]; q8[mt][2] = fmaf(a[2], a[2], q8[mt][2]);
            s8[mt][3] += a[3]; q8[mt][3] = fmaf(a[3], a[3], q8[mt][3]);
            unsigned p0 = (unsigned)f2bf(a[0]) | ((unsigned)f2bf(a[1]) << 16);
            unsigned p1 = (unsigned)f2bf(a[2]) | ((unsigned)f2bf(a[3]) << 16);
            *(uint2*)&Xs[s][ob] = make_uint2(p0, p1);
        }
    {
        int rep = (blockIdx.x & (NREP - 1)) * 256;
        #pragma unroll
        for (int mt = 0; mt < 2; mt++)
            #pragma unroll
            for (int r = 0; r < 4; r++) {
                float sv = row16_sum(s8[mt][r]);
                float qv = row16_sum(q8[mt][r]);
                if ((lane & 15) == 15) {
                    int o = w * 32 + mt * 16 + quad * 4 + r;
                    atomicAdd(&statsOut[rep + o], sv);
                    atomicAdd(&statsOut[rep + 128 + o], qv);
                }
            }
    }
    __syncthreads();
    int c = t & 15, sr = t >> 4;
    #pragma unroll
    for (int i = 0; i < 8; i++) {
        int s = sr + 16 * i;
        uint4 v = *(const uint4*)&Xs[s][c * 8];
        *(uint4*)&yout[(size_t)(s0 + s) * 128 + c * 8] = v;
    }
}

// ---------------- GEMM3: fold replicas + bnparam(2) + MFMA + fused stats3 + fused maxpool (raw fp32 max) ----------------
// maxpool commutes with BN3-affine+relu because sc3 = g3/sqrt(var+eps) >= 0 (g3 = ones).
// y3 is never materialized; raw per-(p,o) maxima go directly into out_feat, finalized in place.
__global__ __launch_bounds__(256) void gemm3_pool_mfma(
        const unsigned short* __restrict__ wb16, const unsigned short* __restrict__ yprev,
        const float* __restrict__ statsPrev, const float* __restrict__ gPrev,
        const float* __restrict__ bePrev, float* __restrict__ statsOut,
        float* __restrict__ out_feat) {
    __shared__ unsigned short Xs[128][136];
    __shared__ float ssc[128], ssh[128];
    __shared__ float pool[8][133];
    int t = threadIdx.x;
    int s0 = blockIdx.x * 128;
    if (t < 128) {
        float sA = 0.f, qA = 0.f;
        #pragma unroll
        for (int r = 0; r < NREP; r++) {
            sA += statsPrev[r * 256 + t];
            qA += statsPrev[r * 256 + 128 + t];
        }
        float mean = sA * (1.f / (float)S);
        float var  = qA * (1.f / (float)S) - mean * mean;
        float sc = gPrev[t] / sqrtf(var + EPSF);
        ssc[t] = sc;
        ssh[t] = bePrev[t] - mean * sc;
    }
    __syncthreads();
    int ss = t >> 1, hh = (t & 1) * 64;
    {
        const uint4* src = (const uint4*)&yprev[(size_t)(s0 + ss) * 128 + hh];
        #pragma unroll
        for (int i = 0; i < 8; i++) {
            uint4 raw = src[i];
            int kb = hh + i * 8;
            float4 c0 = *(float4*)&ssc[kb];
            float4 c1 = *(float4*)&ssc[kb + 4];
            float4 h0 = *(float4*)&ssh[kb];
            float4 h1 = *(float4*)&ssh[kb + 4];
            float f0 = fmaxf(0.f, fmaf(bf2f((unsigned short)(raw.x & 0xFFFF)), c0.x, h0.x));
            float f1 = fmaxf(0.f, fmaf(bf2f((unsigned short)(raw.x >> 16)),    c0.y, h0.y));
            float f2 = fmaxf(0.f, fmaf(bf2f((unsigned short)(raw.y & 0xFFFF)), c0.z, h0.z));
            float f3 = fmaxf(0.f, fmaf(bf2f((unsigned short)(raw.y >> 16)),    c0.w, h0.w));
            float f4 = fmaxf(0.f, fmaf(bf2f((unsigned short)(raw.z & 0xFFFF)), c1.x, h1.x));
            float f5 = fmaxf(0.f, fmaf(bf2f((unsigned short)(raw.z >> 16)),    c1.y, h1.y));
            float f6 = fmaxf(0.f, fmaf(bf2f((unsigned short)(raw.w & 0xFFFF)), c1.z, h1.z));
            float f7 = fmaxf(0.f, fmaf(bf2f((unsigned short)(raw.w >> 16)),    c1.w, h1.w));
            unsigned o0 = (unsigned)f2bf(f0) | ((unsigned)f2bf(f1) << 16);
            unsigned o1 = (unsigned)f2bf(f2) | ((unsigned)f2bf(f3) << 16);
            unsigned o2 = (unsigned)f2bf(f4) | ((unsigned)f2bf(f5) << 16);
            unsigned o3 = (unsigned)f2bf(f6) | ((unsigned)f2bf(f7) << 16);
            *(uint4*)&Xs[ss][kb] = make_uint4(o0, o1, o2, o3);
        }
    }
    __syncthreads();
    int lane = t & 63, w = t >> 6;
    int row16 = lane & 15, quad = lane >> 4;
    floatx4 acc[2][8];
    #pragma unroll
    for (int mt = 0; mt < 2; mt++)
        #pragma unroll
        for (int nt = 0; nt < 8; nt++)
            acc[mt][nt] = (floatx4){0.f, 0.f, 0.f, 0.f};
    #pragma unroll
    for (int kk = 0; kk < 128; kk += 32) {
        short8 a0 = *(const short8*)&wb16[(size_t)(w * 32 + row16) * 128 + kk + quad * 8];
        short8 a1 = *(const short8*)&wb16[(size_t)(w * 32 + 16 + row16) * 128 + kk + quad * 8];
        #pragma unroll
        for (int nt = 0; nt < 8; nt++) {
            short8 bf = *(const short8*)&Xs[nt * 16 + row16][kk + quad * 8];
            acc[0][nt] = __builtin_amdgcn_mfma_f32_16x16x32_bf16(a0, bf, acc[0][nt], 0, 0, 0);
            acc[1][nt] = __builtin_amdgcn_mfma_f32_16x16x32_bf16(a1, bf, acc[1][nt], 0, 0, 0);
        }
    }
    // columns: s = nt*16 + row16 -> pool p_local = nt, pool lane n = row16
    float s8[2][4] = {}, q8[2][4] = {};
    #pragma unroll
    for (int mt = 0; mt < 2; mt++)
        #pragma unroll
        for (int nt = 0; nt < 8; nt++) {
            floatx4 a = acc[mt][nt];
            #pragma unroll
            for (int r = 0; r < 4; r++) {
                float v = a[r];
                s8[mt][r] += v;
                q8[mt][r] = fmaf(v, v, q8[mt][r]);
                float mx = row16_max(v);
                if ((lane & 15) == 15)
                    pool[nt][w * 32 + mt * 16 + quad * 4 + r] = mx;
            }
        }
    {
        int rep = (blockIdx.x & (NREP - 1)) * 256;
        #pragma unroll
        for (int mt = 0; mt < 2; mt++)
            #pragma unroll
            for (int r = 0; r < 4; r++) {
                float sv = row16_sum(s8[mt][r]);
                float qv = row16_sum(q8[mt][r]);
                if ((lane & 15) == 15) {
                    int o = w * 32 + mt * 16 + quad * 4 + r;
                    atomicAdd(&statsOut[rep + o], sv);
                    atomicAdd(&statsOut[rep + 128 + o], qv);
                }
            }
    }
    __syncthreads();
    // store raw maxima: out_feat[b][o][p]
    {
        int b = s0 >> 13;
        int pcol0 = (s0 & (SB - 1)) >> 4;
        int o = t >> 1, half = (t & 1) * 4;
        float4 v = make_float4(pool[half + 0][o], pool[half + 1][o],
                               pool[half + 2][o], pool[half + 3][o]);
        *(float4*)&out_feat[((size_t)b * HID + o) * NP + pcol0 + half] = v;
    }
}

// ---------------- finalize: fold replicas(3) + in-place BN3 affine + relu on pooled raw maxima ----------------
__global__ __launch_bounds__(256) void finalize_kernel(float* __restrict__ out_feat,
        const float* __restrict__ st3, const float* __restrict__ g,
        const float* __restrict__ be) {
    __shared__ float lsc[8], lsh[8];
    int blk = blockIdx.x;                 // 512 blocks x 4096 floats
    int t = threadIdx.x;
    int base = blk * 4096;                // 8 consecutive o-rows within one b
    int o0 = (blk * 8) & 127;
    if (t < 8) {
        int o = o0 + t;
        float sA = 0.f, qA = 0.f;
        #pragma unroll
        for (int r = 0; r < NREP; r++) {
            sA += st3[r * 256 + o];
            qA += st3[r * 256 + 128 + o];
        }
        float mean = sA * (1.f / (float)S);
        float var  = qA * (1.f / (float)S) - mean * mean;
        float sc = g[o] / sqrtf(var + EPSF);
        lsc[t] = sc;
        lsh[t] = be[o] - mean * sc;
    }
    __syncthreads();
    int i = base + t * 16;
    int oloc = (t * 16) >> 9;             // 0..7
    float sc = lsc[oloc], sh = lsh[oloc];
    float4* p = (float4*)&out_feat[i];
    #pragma unroll
    for (int j = 0; j < 4; j++) {
        float4 v = p[j];
        v.x = fmaxf(0.f, fmaf(v.x, sc, sh));
        v.y = fmaxf(0.f, fmaf(v.y, sc, sh));
        v.z = fmaxf(0.f, fmaf(v.z, sc, sh));
        v.w = fmaxf(0.f, fmaf(v.w, sc, sh));
        p[j] = v;
    }
}

extern "C" void kernel_launch(void* const* d_in, const int* in_sizes, int n_in,
                              void* d_out, int out_size, void* d_ws, size_t ws_size,
                              hipStream_t stream) {
    const float* xyz  = (const float*)d_in[0];
    const float* feat = (const float*)d_in[1];
    const float* seed = (const float*)d_in[2];
    const float* w1 = (const float*)d_in[3];
    const float* g1 = (const float*)d_in[4];
    const float* be1 = (const float*)d_in[5];
    const float* w2 = (const float*)d_in[6];
    const float* g2 = (const float*)d_in[7];
    const float* be2 = (const float*)d_in[8];
    const float* w3 = (const float*)d_in[9];
    const float* g3 = (const float*)d_in[10];
    const float* be3 = (const float*)d_in[11];

    float* out_newxyz = (float*)d_out;                 // (B,NP,3)
    float* out_feat   = out_newxyz + B * NP * 3;       // (B,HID,NP)
    float* out_inds   = out_feat + B * HID * NP;       // (B,NP) as float

    float* stats = (float*)d_ws;                       // 3 layers x NREP x [sum(128)|sq(128)]
    int*   inds  = (int*)(stats + 3 * LSTRIDE);
    int*   idx   = inds + B * NP;
    unsigned short* w1fb  = (unsigned short*)(idx + (size_t)B * NP * NS);
    unsigned short* w2b   = w1fb + 256 * HID;
    unsigned short* w3b   = w2b + HID * HID;
    unsigned short* featT = w3b + HID * HID;           // B*N*256 bf16
    unsigned short* y1    = featT + (size_t)B * N * 256;   // S*128 bf16
    unsigned short* y2    = featT;                     // alias: featT dead after gemm1

    size_t need = (size_t)(3 * LSTRIDE) * 4 + (size_t)B * NP * 4 + (size_t)B * NP * NS * 4
                + (size_t)(256 * HID + 2 * HID * HID) * 2
                + 2ull * (size_t)B * N * 256 * 2;
    if (ws_size < need) return;

    fused_front_kernel<<<FPS_BLOCKS + TR_BLOCKS + PREP_BLOCKS, 512, 0, stream>>>(
        seed, xyz, feat, w1, w2, w3, featT, w1fb, w2b, w3b, stats,
        inds, out_newxyz, out_inds);
    ballquery_kernel<<<B * 32, 256, 0, stream>>>(xyz, out_newxyz, idx);
    gemm1_mfma<<<S / 128, 256, 0, stream>>>(w1fb, w1, featT, out_newxyz, xyz, idx, y1, stats);
    gemm_bn_mfma<<<S / 128, 256, 0, stream>>>(w2b, y1, stats, g1, be1, stats + LSTRIDE, y2);
    gemm3_pool_mfma<<<S / 128, 256, 0, stream>>>(w3b, y2, stats + LSTRIDE, g2, be2, stats + 2 * LSTRIDE, out_feat);
    finalize_kernel<<<(B * HID * NP) / 4096, 256, 0, stream>>>(out_feat, stats + 2 * LSTRIDE, g3, be3);
}

// Round 5
// 711.352 us; speedup vs baseline: 1.7400x; 1.0402x over previous
//
#include <hip/hip_runtime.h>
#include <cstdint>
#include <cstddef>

#define B   32
#define N   4096
#define NP  512
#define NS  16
#define C   256
#define CIN 259
#define HID 128
#define SB  (NP*NS)      // 8192 columns per batch
#define S   (B*SB)       // 262144 total columns
#define EPSF 1e-5f

#define FPS_BLOCKS 32
#define TR_BLOCKS  (B*256)   // 8192 transpose tiles
#define PREP_BLOCKS 64

#define NREP 32              // stats replicas (atomic chain depth = blocks/NREP = 64)
#define LSTRIDE (NREP*256)   // floats per stats layer

typedef __attribute__((ext_vector_type(8))) short short8;
typedef __attribute__((ext_vector_type(4))) float floatx4;

__device__ __forceinline__ float bf2f(unsigned short u) {
    return __uint_as_float(((unsigned)u) << 16);
}
__device__ __forceinline__ unsigned short f2bf(float f) {
    unsigned u = __float_as_uint(f);
    return (unsigned short)((u + 0x7FFFu + ((u >> 16) & 1u)) >> 16);
}

// single 6-step DPP max chain on a packed u64 key (nonneg); lane 63 holds the wave max.
// bound_ctrl/row_mask zero-fill loses against any nonneg key.
__device__ __forceinline__ unsigned long long wave_max_u64(unsigned long long x) {
#define WM64_STEP(ctrl, rmask) { \
        unsigned lo_ = (unsigned)x, hi_ = (unsigned)(x >> 32); \
        unsigned ylo_ = (unsigned)__builtin_amdgcn_update_dpp(0, (int)lo_, ctrl, rmask, 0xf, true); \
        unsigned yhi_ = (unsigned)__builtin_amdgcn_update_dpp(0, (int)hi_, ctrl, rmask, 0xf, true); \
        unsigned long long y_ = ((unsigned long long)yhi_ << 32) | ylo_; \
        x = (y_ > x) ? y_ : x; }
    WM64_STEP(0x111, 0xf)
    WM64_STEP(0x112, 0xf)
    WM64_STEP(0x114, 0xf)
    WM64_STEP(0x118, 0xf)
    WM64_STEP(0x142, 0xa)
    WM64_STEP(0x143, 0xc)
#undef WM64_STEP
    return x;
}

__device__ __forceinline__ unsigned long long umax64(unsigned long long a, unsigned long long b) {
    return (b > a) ? b : a;
}

// sum over each 16-lane row; lanes with (lane&15)==15 hold the full row sum
__device__ __forceinline__ float row16_sum(float x) {
    float y;
    y = __int_as_float(__builtin_amdgcn_update_dpp(0, __float_as_int(x), 0x111, 0xf, 0xf, true)); x += y;
    y = __int_as_float(__builtin_amdgcn_update_dpp(0, __float_as_int(x), 0x112, 0xf, 0xf, true)); x += y;
    y = __int_as_float(__builtin_amdgcn_update_dpp(0, __float_as_int(x), 0x114, 0xf, 0xf, true)); x += y;
    y = __int_as_float(__builtin_amdgcn_update_dpp(0, __float_as_int(x), 0x118, 0xf, 0xf, true)); x += y;
    return x;
}
// max over each 16-lane row (invalid lanes keep old value); lane&15==15 holds row max
__device__ __forceinline__ float row16_max(float x) {
    int xi = __float_as_int(x);
    float y;
    y = __int_as_float(__builtin_amdgcn_update_dpp(xi, xi, 0x111, 0xf, 0xf, false)); x = fmaxf(x, y); xi = __float_as_int(x);
    y = __int_as_float(__builtin_amdgcn_update_dpp(xi, xi, 0x112, 0xf, 0xf, false)); x = fmaxf(x, y); xi = __float_as_int(x);
    y = __int_as_float(__builtin_amdgcn_update_dpp(xi, xi, 0x114, 0xf, 0xf, false)); x = fmaxf(x, y); xi = __float_as_int(x);
    y = __int_as_float(__builtin_amdgcn_update_dpp(xi, xi, 0x118, 0xf, 0xf, false)); x = fmaxf(x, y);
    return x;
}

// ---------------- fused front: FPS + feat transpose(bf16) + weight prep(bf16) ----------------
__global__ __launch_bounds__(512) void fused_front_kernel(
        const float* __restrict__ seed, const float* __restrict__ xyz,
        const float* __restrict__ feat, const float* __restrict__ w1,
        const float* __restrict__ w2, const float* __restrict__ w3,
        unsigned short* __restrict__ featT, unsigned short* __restrict__ w1fb,
        unsigned short* __restrict__ w2b, unsigned short* __restrict__ w3b,
        float* __restrict__ stats, int* __restrict__ inds,
        float* __restrict__ out_newxyz, float* __restrict__ out_inds_f) {
    __shared__ float smem[3 * N];                       // 48 KB: transpose tile | FPS sx/sy/sz
    __shared__ __align__(16) unsigned long long skey[2][8];   // [parity][wave] wave-max key
    __shared__ int lhist[NP];                           // FPS selection history (LDS only)
    int bid = blockIdx.x;
    int t = threadIdx.x;

    if (bid >= FPS_BLOCKS) {
        int hb = bid - FPS_BLOCKS;
        if (hb < TR_BLOCKS) {
            // ---- transpose feat (B,C,N) fp32 -> featT (B,N,256) bf16, 32x128 tile ----
            float* ls = smem;
            int b2 = hb >> 8, rem = hb & 255;
            int ct = rem >> 5, jt = rem & 31;
            int c0 = ct * 32, j0 = jt * 128;
            const float* src = feat + (size_t)b2 * C * N;
            #pragma unroll
            for (int i = 0; i < 8; i++) {
                int lin = t + 512 * i;
                int jj = lin & 127, cc = lin >> 7;
                ls[cc * 129 + jj] = src[(size_t)(c0 + cc) * N + j0 + jj];
            }
            __syncthreads();
            int c8 = t & 3, jj = t >> 2;
            unsigned pk[4];
            #pragma unroll
            for (int q = 0; q < 4; q++) {
                float f0 = ls[(c8 * 8 + 2 * q) * 129 + jj];
                float f1 = ls[(c8 * 8 + 2 * q + 1) * 129 + jj];
                pk[q] = (unsigned)f2bf(f0) | ((unsigned)f2bf(f1) << 16);
            }
            *(uint4*)&featT[((size_t)b2 * N + j0 + jj) * 256 + c0 + c8 * 8] =
                make_uint4(pk[0], pk[1], pk[2], pk[3]);
        } else {
            // ---- prep: weights -> bf16 [o][k]; zero stats (3 layers x NREP x 256) ----
            int i0 = (hb - TR_BLOCKS) * 512 + t;
            if (i0 < 256 * HID) { int o = i0 >> 8, k = i0 & 255; w1fb[i0] = f2bf(w1[o * CIN + 3 + k]); }
            if (i0 < HID * HID) { w2b[i0] = f2bf(w2[i0]); w3b[i0] = f2bf(w3[i0]); }
            if (i0 < 3 * LSTRIDE) stats[i0] = 0.f;
        }
        return;
    }

    // ---- FPS for batch b = bid: zero global memory ops inside the loop ----
    int b = bid;
    const float* sp = seed + (size_t)b * N * 3;
    float* sx = smem;
    float* sy = smem + N;
    float* sz = smem + 2 * N;
    float px[8], py[8], pz[8], dloc[8];
    #pragma unroll
    for (int u = 0; u < 8; u++) {
        int i = t + 512 * u;
        float x = sp[i * 3 + 0], y = sp[i * 3 + 1], z = sp[i * 3 + 2];
        sx[i] = x; sy[i] = y; sz[i] = z;
        px[u] = x; py[u] = y; pz[u] = z;
        dloc[u] = 1e10f;
    }
    if (t == 0) lhist[0] = 0;
    float lx = sp[0], ly = sp[1], lz = sp[2];   // first selected point = index 0
    int lane = t & 63, w = t >> 6;
    __syncthreads();
    for (int k = 1; k < NP; k++) {
        float bv = -1.f; int bi = 0;
        #pragma unroll
        for (int u = 0; u < 8; u++) {
            int i = t + 512 * u;
            float dx = __fsub_rn(px[u], lx);
            float dy = __fsub_rn(py[u], ly);
            float dz = __fsub_rn(pz[u], lz);
            float d  = __fadd_rn(__fadd_rn(__fmul_rn(dx, dx), __fmul_rn(dy, dy)), __fmul_rn(dz, dz));
            float dm = fminf(dloc[u], d);
            dloc[u] = dm;
            bool bt = dm > bv;            // i ascending in u -> strict > keeps min index
            bv = bt ? dm : bv;
            bi = bt ? i : bi;
        }
        // packed key: (dist_bits << 12) | (4095 - idx); u64 max == (max dist, then min idx)
        unsigned long long key =
            (((unsigned long long)(unsigned)__float_as_int(bv)) << 12) | (unsigned)(4095 - bi);
        unsigned long long wmax = wave_max_u64(key);   // valid in lane 63
        int par = k & 1;
        if (lane == 63) skey[par][w] = wmax;
        __syncthreads();
        // cross-wave: read 8 keys as 4x b128, 3-level tree, then broadcast coord read from LDS
        const ulonglong2* kp = (const ulonglong2*)&skey[par][0];
        ulonglong2 q0 = kp[0], q1 = kp[1], q2 = kp[2], q3 = kp[3];
        unsigned long long a = umax64(q0.x, q0.y);
        unsigned long long c2 = umax64(q1.x, q1.y);
        unsigned long long e = umax64(q2.x, q2.y);
        unsigned long long g = umax64(q3.x, q3.y);
        unsigned long long h = umax64(umax64(a, c2), umax64(e, g));
        int gi = 4095 - (int)(h & 0xFFFull);
        lx = sx[gi]; ly = sy[gi]; lz = sz[gi];
        if (t == 0) lhist[k] = gi;
    }
    __syncthreads();
    {
        int p = t;   // 512 threads cover NP=512
        int j = lhist[p];
        const float* xb = xyz + ((size_t)b * N + j) * 3;
        float* ob = out_newxyz + ((size_t)b * NP + p) * 3;
        ob[0] = xb[0]; ob[1] = xb[1]; ob[2] = xb[2];
        out_inds_f[b * NP + p] = (float)j;
    }
}

// ---------------- ball query: wave-parallel ballot scan, first NS by index ----------------
__global__ __launch_bounds__(256) void ballquery_kernel(const float* __restrict__ xyz,
        const float* __restrict__ newxyz, int* __restrict__ idx) {
    __shared__ float sx[N], sy[N], sz[N];
    int blk = blockIdx.x;
    int b   = blk >> 5;
    int q00 = (blk & 31) * 16;
    int t = threadIdx.x, lane = t & 63, w = t >> 6;
    const float* xb = xyz + (size_t)b * N * 3;
    for (int i = t; i < N; i += 256) { sx[i] = xb[i * 3]; sy[i] = xb[i * 3 + 1]; sz[i] = xb[i * 3 + 2]; }
    __syncthreads();
    for (int qi = 0; qi < 4; qi++) {
        int q = q00 + w * 4 + qi;
        const float* nq = newxyz + ((size_t)(b * NP + q)) * 3;
        float qx = nq[0], qy = nq[1], qz = nq[2];
        int* out = idx + ((size_t)(b * NP + q)) * NS;
        int cnt = 0, first = -1;
        for (int it = 0; it < 64; it++) {
            int j = it * 64 + lane;
            float dx = __fsub_rn(sx[j], qx);
            float dy = __fsub_rn(sy[j], qy);
            float dz = __fsub_rn(sz[j], qz);
            float d2 = __fadd_rn(__fadd_rn(__fmul_rn(dx, dx), __fmul_rn(dy, dy)), __fmul_rn(dz, dz));
            bool inb = d2 < 0.09f;
            unsigned long long m = __ballot(inb);
            if (m) {
                if (first < 0) first = it * 64 + __builtin_ctzll(m);
                if (inb) {
                    int r = cnt + __popcll(m & ((1ull << lane) - 1ull));
                    if (r < NS) out[r] = j;
                }
                cnt += __popcll(m);
                if (cnt >= NS) break;
            }
        }
        if (cnt < NS && lane >= cnt && lane < NS) out[lane] = first;
    }
}

// ---------------- GEMM1 (MFMA bf16): y1[s][o] = w1feat . gathered featT + xyz epilogue + fused stats ----------------
// XCD-aware swizzle: physical p -> XCD p%8; logical ls = (p&7)*256 + (p>>3) gives each XCD a
// contiguous 256-block run so the concurrent gather window (~1.5 batches, 3MB featT) fits its 4MB L2.
__global__ __launch_bounds__(256) void gemm1_mfma(
        const unsigned short* __restrict__ w1fb, const float* __restrict__ w1raw,
        const unsigned short* __restrict__ featT, const float* __restrict__ newxyz,
        const float* __restrict__ xyz, const int* __restrict__ idx,
        unsigned short* __restrict__ y1, float* __restrict__ statsOut) {
    __shared__ unsigned short Xs[128][136];       // [s][k] slab, reused as [s][o] out tile
    __shared__ float xn0[128], xn1[128], xn2[128];
    __shared__ int jl[128];
    int t = threadIdx.x;
    int pb = blockIdx.x;
    int lsb = (pb & 7) * 256 + (pb >> 3);
    int s0 = lsb * 128;
    int b = s0 >> 13;
    if (t < 128) {
        int pn = (s0 & (SB - 1)) + t;
        int p = pn >> 4, n = pn & 15;
        int j = idx[((size_t)(b * NP + p)) * NS + n];
        jl[t] = j;
        const float* xb = xyz + ((size_t)(b * N + j)) * 3;
        const float* nq = newxyz + ((size_t)(b * NP + p)) * 3;
        xn0[t] = (xb[0] - nq[0]) / 0.3f;
        xn1[t] = (xb[1] - nq[1]) / 0.3f;
        xn2[t] = (xb[2] - nq[2]) / 0.3f;
    }
    __syncthreads();
    int lane = t & 63, w = t >> 6;
    int row16 = lane & 15, quad = lane >> 4;
    floatx4 acc[2][8];
    #pragma unroll
    for (int mt = 0; mt < 2; mt++)
        #pragma unroll
        for (int nt = 0; nt < 8; nt++)
            acc[mt][nt] = (floatx4){0.f, 0.f, 0.f, 0.f};
    int ss = t >> 1, hh = (t & 1) * 64;
    const unsigned short* grow = featT + ((size_t)b * N + jl[ss]) * 256 + hh;
    for (int slab = 0; slab < 2; slab++) {
        int k0 = slab * 128;
        {
            const uint4* src = (const uint4*)(grow + k0);
            #pragma unroll
            for (int i = 0; i < 8; i++)
                *(uint4*)&Xs[ss][hh + i * 8] = src[i];
        }
        __syncthreads();
        #pragma unroll
        for (int kk = 0; kk < 128; kk += 32) {
            short8 a0 = *(const short8*)&w1fb[(size_t)(w * 32 + row16) * 256 + k0 + kk + quad * 8];
            short8 a1 = *(const short8*)&w1fb[(size_t)(w * 32 + 16 + row16) * 256 + k0 + kk + quad * 8];
            #pragma unroll
            for (int nt = 0; nt < 8; nt++) {
                short8 bf = *(const short8*)&Xs[nt * 16 + row16][kk + quad * 8];
                acc[0][nt] = __builtin_amdgcn_mfma_f32_16x16x32_bf16(a0, bf, acc[0][nt], 0, 0, 0);
                acc[1][nt] = __builtin_amdgcn_mfma_f32_16x16x32_bf16(a1, bf, acc[1][nt], 0, 0, 0);
            }
        }
        __syncthreads();
    }
    // epilogue: + w1_xyz . xn (fp32), pack bf16, tile [s][o], coalesced global write + stats
    float wa[8], wbv[8], wc[8];
    #pragma unroll
    for (int mt = 0; mt < 2; mt++)
        #pragma unroll
        for (int r = 0; r < 4; r++) {
            int o = w * 32 + mt * 16 + quad * 4 + r;
            const float* wr = w1raw + (size_t)o * CIN;
            wa[mt * 4 + r] = wr[0]; wbv[mt * 4 + r] = wr[1]; wc[mt * 4 + r] = wr[2];
        }
    float x0l[8], x1l[8], x2l[8];
    #pragma unroll
    for (int nt = 0; nt < 8; nt++) {
        int s = nt * 16 + row16;
        x0l[nt] = xn0[s]; x1l[nt] = xn1[s]; x2l[nt] = xn2[s];
    }
    float s8[2][4] = {}, q8[2][4] = {};
    #pragma unroll
    for (int mt = 0; mt < 2; mt++)
        #pragma unroll
        for (int nt = 0; nt < 8; nt++) {
            int s = nt * 16 + row16;
            int ob = w * 32 + mt * 16 + quad * 4;
            floatx4 a = acc[mt][nt];
            float v0 = a[0] + wa[mt*4+0]*x0l[nt] + wbv[mt*4+0]*x1l[nt] + wc[mt*4+0]*x2l[nt];
            float v1 = a[1] + wa[mt*4+1]*x0l[nt] + wbv[mt*4+1]*x1l[nt] + wc[mt*4+1]*x2l[nt];
            float v2 = a[2] + wa[mt*4+2]*x0l[nt] + wbv[mt*4+2]*x1l[nt] + wc[mt*4+2]*x2l[nt];
            float v3 = a[3] + wa[mt*4+3]*x0l[nt] + wbv[mt*4+3]*x1l[nt] + wc[mt*4+3]*x2l[nt];
            s8[mt][0] += v0; q8[mt][0] = fmaf(v0, v0, q8[mt][0]);
            s8[mt][1] += v1; q8[mt][1] = fmaf(v1, v1, q8[mt][1]);
            s8[mt][2] += v2; q8[mt][2] = fmaf(v2, v2, q8[mt][2]);
            s8[mt][3] += v3; q8[mt][3] = fmaf(v3, v3, q8[mt][3]);
            unsigned p0 = (unsigned)f2bf(v0) | ((unsigned)f2bf(v1) << 16);
            unsigned p1 = (unsigned)f2bf(v2) | ((unsigned)f2bf(v3) << 16);
            *(uint2*)&Xs[s][ob] = make_uint2(p0, p1);
        }
    // per-channel stats into replica slot (chain depth = blocks/NREP)
    {
        int rep = (pb & (NREP - 1)) * 256;
        #pragma unroll
        for (int mt = 0; mt < 2; mt++)
            #pragma unroll
            for (int r = 0; r < 4; r++) {
                float sv = row16_sum(s8[mt][r]);
                float qv = row16_sum(q8[mt][r]);
                if ((lane & 15) == 15) {
                    int o = w * 32 + mt * 16 + quad * 4 + r;
                    atomicAdd(&statsOut[rep + o], sv);
                    atomicAdd(&statsOut[rep + 128 + o], qv);
                }
            }
    }
    __syncthreads();
    int c = t & 15, sr = t >> 4;
    #pragma unroll
    for (int i = 0; i < 8; i++) {
        int s = sr + 16 * i;
        uint4 v = *(const uint4*)&Xs[s][c * 8];
        *(uint4*)&y1[(size_t)(s0 + s) * 128 + c * 8] = v;
    }
}

// ---------------- GEMM2 (MFMA bf16): fold replicas + bnparam + X=relu(affine(yprev)), Y=W*X + fused stats ----------------
__global__ __launch_bounds__(256) void gemm_bn_mfma(
        const unsigned short* __restrict__ wb16, const unsigned short* __restrict__ yprev,
        const float* __restrict__ statsPrev, const float* __restrict__ gPrev,
        const float* __restrict__ bePrev, float* __restrict__ statsOut,
        unsigned short* __restrict__ yout) {
    __shared__ unsigned short Xs[128][136];
    __shared__ float ssc[128], ssh[128];
    int t = threadIdx.x;
    int s0 = blockIdx.x * 128;
    if (t < 128) {
        float sA = 0.f, qA = 0.f;
        #pragma unroll
        for (int r = 0; r < NREP; r++) {
            sA += statsPrev[r * 256 + t];
            qA += statsPrev[r * 256 + 128 + t];
        }
        float mean = sA * (1.f / (float)S);
        float var  = qA * (1.f / (float)S) - mean * mean;
        float sc = gPrev[t] / sqrtf(var + EPSF);
        ssc[t] = sc;
        ssh[t] = bePrev[t] - mean * sc;
    }
    __syncthreads();
    int ss = t >> 1, hh = (t & 1) * 64;
    {
        const uint4* src = (const uint4*)&yprev[(size_t)(s0 + ss) * 128 + hh];
        #pragma unroll
        for (int i = 0; i < 8; i++) {
            uint4 raw = src[i];
            int kb = hh + i * 8;
            float4 c0 = *(float4*)&ssc[kb];
            float4 c1 = *(float4*)&ssc[kb + 4];
            float4 h0 = *(float4*)&ssh[kb];
            float4 h1 = *(float4*)&ssh[kb + 4];
            float f0 = fmaxf(0.f, fmaf(bf2f((unsigned short)(raw.x & 0xFFFF)), c0.x, h0.x));
            float f1 = fmaxf(0.f, fmaf(bf2f((unsigned short)(raw.x >> 16)),    c0.y, h0.y));
            float f2 = fmaxf(0.f, fmaf(bf2f((unsigned short)(raw.y & 0xFFFF)), c0.z, h0.z));
            float f3 = fmaxf(0.f, fmaf(bf2f((unsigned short)(raw.y >> 16)),    c0.w, h0.w));
            float f4 = fmaxf(0.f, fmaf(bf2f((unsigned short)(raw.z & 0xFFFF)), c1.x, h1.x));
            float f5 = fmaxf(0.f, fmaf(bf2f((unsigned short)(raw.z >> 16)),    c1.y, h1.y));
            float f6 = fmaxf(0.f, fmaf(bf2f((unsigned short)(raw.w & 0xFFFF)), c1.z, h1.z));
            float f7 = fmaxf(0.f, fmaf(bf2f((unsigned short)(raw.w >> 16)),    c1.w, h1.w));
            unsigned o0 = (unsigned)f2bf(f0) | ((unsigned)f2bf(f1) << 16);
            unsigned o1 = (unsigned)f2bf(f2) | ((unsigned)f2bf(f3) << 16);
            unsigned o2 = (unsigned)f2bf(f4) | ((unsigned)f2bf(f5) << 16);
            unsigned o3 = (unsigned)f2bf(f6) | ((unsigned)f2bf(f7) << 16);
            *(uint4*)&Xs[ss][kb] = make_uint4(o0, o1, o2, o3);
        }
    }
    __syncthreads();
    int lane = t & 63, w = t >> 6;
    int row16 = lane & 15, quad = lane >> 4;
    floatx4 acc[2][8];
    #pragma unroll
    for (int mt = 0; mt < 2; mt++)
        #pragma unroll
        for (int nt = 0; nt < 8; nt++)
            acc[mt][nt] = (floatx4){0.f, 0.f, 0.f, 0.f};
    #pragma unroll
    for (int kk = 0; kk < 128; kk += 32) {
        short8 a0 = *(const short8*)&wb16[(size_t)(w * 32 + row16) * 128 + kk + quad * 8];
        short8 a1 = *(const short8*)&wb16[(size_t)(w * 32 + 16 + row16) * 128 + kk + quad * 8];
        #pragma unroll
        for (int nt = 0; nt < 8; nt++) {
            short8 bf = *(const short8*)&Xs[nt * 16 + row16][kk + quad * 8];
            acc[0][nt] = __builtin_amdgcn_mfma_f32_16x16x32_bf16(a0, bf, acc[0][nt], 0, 0, 0);
            acc[1][nt] = __builtin_amdgcn_mfma_f32_16x16x32_bf16(a1, bf, acc[1][nt], 0, 0, 0);
        }
    }
    __syncthreads();
    float s8[2][4] = {}, q8[2][4] = {};
    #pragma unroll
    for (int mt = 0; mt < 2; mt++)
        #pragma unroll
        for (int nt = 0; nt < 8; nt++) {
            int s = nt * 16 + row16;
            int ob = w * 32 + mt * 16 + quad * 4;
            floatx4 a = acc[mt][nt];
            s8[mt][0] += a[0]; q8[mt][0] = fmaf(a[0], a[0], q8[mt][0]);
            s8[mt][1] += a[1]; q8[mt][1] = fmaf(a[1], a[1], q8[mt][1]);
            s8[mt][2] += a[2]; q8[mt][2] = fmaf(a[2], a[2], q8[mt][2]);
            s8[mt][3] += a[3]; q8[mt][3] = fmaf(a[3], a[3], q8[mt][3]);
            unsigned p0 = (unsigned)f2bf(a[0]) | ((unsigned)f2bf(a[1]) << 16);
            unsigned p1 = (unsigned)f2bf(a[2]) | ((unsigned)f2bf(a[3]) << 16);
            *(uint2*)&Xs[s][ob] = make_uint2(p0, p1);
        }
    {
        int rep = (blockIdx.x & (NREP - 1)) * 256;
        #pragma unroll
        for (int mt = 0; mt < 2; mt++)
            #pragma unroll
            for (int r = 0; r < 4; r++) {
                float sv = row16_sum(s8[mt][r]);
                float qv = row16_sum(q8[mt][r]);
                if ((lane & 15) == 15) {
                    int o = w * 32 + mt * 16 + quad * 4 + r;
                    atomicAdd(&statsOut[rep + o], sv);
                    atomicAdd(&statsOut[rep + 128 + o], qv);
                }
            }
    }
    __syncthreads();
    int c = t & 15, sr = t >> 4;
    #pragma unroll
    for (int i = 0; i < 8; i++) {
        int s = sr + 16 * i;
        uint4 v = *(const uint4*)&Xs[s][c * 8];
        *(uint4*)&yout[(size_t)(s0 + s) * 128 + c * 8] = v;
    }
}

// ---------------- GEMM3: fold replicas + bnparam(2) + MFMA + fused stats3 + fused maxpool (raw fp32 max) ----------------
// maxpool commutes with BN3-affine+relu because sc3 = g3/sqrt(var+eps) >= 0 (g3 = ones).
// y3 is never materialized; raw per-(p,o) maxima go directly into out_feat, finalized in place.
__global__ __launch_bounds__(256) void gemm3_pool_mfma(
        const unsigned short* __restrict__ wb16, const unsigned short* __restrict__ yprev,
        const float* __restrict__ statsPrev, const float* __restrict__ gPrev,
        const float* __restrict__ bePrev, float* __restrict__ statsOut,
        float* __restrict__ out_feat) {
    __shared__ unsigned short Xs[128][136];
    __shared__ float ssc[128], ssh[128];
    __shared__ float pool[8][133];
    int t = threadIdx.x;
    int s0 = blockIdx.x * 128;
    if (t < 128) {
        float sA = 0.f, qA = 0.f;
        #pragma unroll
        for (int r = 0; r < NREP; r++) {
            sA += statsPrev[r * 256 + t];
            qA += statsPrev[r * 256 + 128 + t];
        }
        float mean = sA * (1.f / (float)S);
        float var  = qA * (1.f / (float)S) - mean * mean;
        float sc = gPrev[t] / sqrtf(var + EPSF);
        ssc[t] = sc;
        ssh[t] = bePrev[t] - mean * sc;
    }
    __syncthreads();
    int ss = t >> 1, hh = (t & 1) * 64;
    {
        const uint4* src = (const uint4*)&yprev[(size_t)(s0 + ss) * 128 + hh];
        #pragma unroll
        for (int i = 0; i < 8; i++) {
            uint4 raw = src[i];
            int kb = hh + i * 8;
            float4 c0 = *(float4*)&ssc[kb];
            float4 c1 = *(float4*)&ssc[kb + 4];
            float4 h0 = *(float4*)&ssh[kb];
            float4 h1 = *(float4*)&ssh[kb + 4];
            float f0 = fmaxf(0.f, fmaf(bf2f((unsigned short)(raw.x & 0xFFFF)), c0.x, h0.x));
            float f1 = fmaxf(0.f, fmaf(bf2f((unsigned short)(raw.x >> 16)),    c0.y, h0.y));
            float f2 = fmaxf(0.f, fmaf(bf2f((unsigned short)(raw.y & 0xFFFF)), c0.z, h0.z));
            float f3 = fmaxf(0.f, fmaf(bf2f((unsigned short)(raw.y >> 16)),    c0.w, h0.w));
            float f4 = fmaxf(0.f, fmaf(bf2f((unsigned short)(raw.z & 0xFFFF)), c1.x, h1.x));
            float f5 = fmaxf(0.f, fmaf(bf2f((unsigned short)(raw.z >> 16)),    c1.y, h1.y));
            float f6 = fmaxf(0.f, fmaf(bf2f((unsigned short)(raw.w & 0xFFFF)), c1.z, h1.z));
            float f7 = fmaxf(0.f, fmaf(bf2f((unsigned short)(raw.w >> 16)),    c1.w, h1.w));
            unsigned o0 = (unsigned)f2bf(f0) | ((unsigned)f2bf(f1) << 16);
            unsigned o1 = (unsigned)f2bf(f2) | ((unsigned)f2bf(f3) << 16);
            unsigned o2 = (unsigned)f2bf(f4) | ((unsigned)f2bf(f5) << 16);
            unsigned o3 = (unsigned)f2bf(f6) | ((unsigned)f2bf(f7) << 16);
            *(uint4*)&Xs[ss][kb] = make_uint4(o0, o1, o2, o3);
        }
    }
    __syncthreads();
    int lane = t & 63, w = t >> 6;
    int row16 = lane & 15, quad = lane >> 4;
    floatx4 acc[2][8];
    #pragma unroll
    for (int mt = 0; mt < 2; mt++)
        #pragma unroll
        for (int nt = 0; nt < 8; nt++)
            acc[mt][nt] = (floatx4){0.f, 0.f, 0.f, 0.f};
    #pragma unroll
    for (int kk = 0; kk < 128; kk += 32) {
        short8 a0 = *(const short8*)&wb16[(size_t)(w * 32 + row16) * 128 + kk + quad * 8];
        short8 a1 = *(const short8*)&wb16[(size_t)(w * 32 + 16 + row16) * 128 + kk + quad * 8];
        #pragma unroll
        for (int nt = 0; nt < 8; nt++) {
            short8 bf = *(const short8*)&Xs[nt * 16 + row16][kk + quad * 8];
            acc[0][nt] = __builtin_amdgcn_mfma_f32_16x16x32_bf16(a0, bf, acc[0][nt], 0, 0, 0);
            acc[1][nt] = __builtin_amdgcn_mfma_f32_16x16x32_bf16(a1, bf, acc[1][nt], 0, 0, 0);
        }
    }
    // columns: s = nt*16 + row16 -> pool p_local = nt, pool lane n = row16
    float s8[2][4] = {}, q8[2][4] = {};
    #pragma unroll
    for (int mt = 0; mt < 2; mt++)
        #pragma unroll
        for (int nt = 0; nt < 8; nt++) {
            floatx4 a = acc[mt][nt];
            #pragma unroll
            for (int r = 0; r < 4; r++) {
                float v = a[r];
                s8[mt][r] += v;
                q8[mt][r] = fmaf(v, v, q8[mt][r]);
                float mx = row16_max(v);
                if ((lane & 15) == 15)
                    pool[nt][w * 32 + mt * 16 + quad * 4 + r] = mx;
            }
        }
    {
        int rep = (blockIdx.x & (NREP - 1)) * 256;
        #pragma unroll
        for (int mt = 0; mt < 2; mt++)
            #pragma unroll
            for (int r = 0; r < 4; r++) {
                float sv = row16_sum(s8[mt][r]);
                float qv = row16_sum(q8[mt][r]);
                if ((lane & 15) == 15) {
                    int o = w * 32 + mt * 16 + quad * 4 + r;
                    atomicAdd(&statsOut[rep + o], sv);
                    atomicAdd(&statsOut[rep + 128 + o], qv);
                }
            }
    }
    __syncthreads();
    // store raw maxima: out_feat[b][o][p]
    {
        int b = s0 >> 13;
        int pcol0 = (s0 & (SB - 1)) >> 4;
        int o = t >> 1, half = (t & 1) * 4;
        float4 v = make_float4(pool[half + 0][o], pool[half + 1][o],
                               pool[half + 2][o], pool[half + 3][o]);
        *(float4*)&out_feat[((size_t)b * HID + o) * NP + pcol0 + half] = v;
    }
}

// ---------------- finalize: fold replicas(3) + in-place BN3 affine + relu on pooled raw maxima ----------------
__global__ __launch_bounds__(256) void finalize_kernel(float* __restrict__ out_feat,
        const float* __restrict__ st3, const float* __restrict__ g,
        const float* __restrict__ be) {
    __shared__ float lsc[8], lsh[8];
    int blk = blockIdx.x;                 // 512 blocks x 4096 floats
    int t = threadIdx.x;
    int base = blk * 4096;                // 8 consecutive o-rows within one b
    int o0 = (blk * 8) & 127;
    if (t < 8) {
        int o = o0 + t;
        float sA = 0.f, qA = 0.f;
        #pragma unroll
        for (int r = 0; r < NREP; r++) {
            sA += st3[r * 256 + o];
            qA += st3[r * 256 + 128 + o];
        }
        float mean = sA * (1.f / (float)S);
        float var  = qA * (1.f / (float)S) - mean * mean;
        float sc = g[o] / sqrtf(var + EPSF);
        lsc[t] = sc;
        lsh[t] = be[o] - mean * sc;
    }
    __syncthreads();
    int i = base + t * 16;
    int oloc = (t * 16) >> 9;             // 0..7
    float sc = lsc[oloc], sh = lsh[oloc];
    float4* p = (float4*)&out_feat[i];
    #pragma unroll
    for (int j = 0; j < 4; j++) {
        float4 v = p[j];
        v.x = fmaxf(0.f, fmaf(v.x, sc, sh));
        v.y = fmaxf(0.f, fmaf(v.y, sc, sh));
        v.z = fmaxf(0.f, fmaf(v.z, sc, sh));
        v.w = fmaxf(0.f, fmaf(v.w, sc, sh));
        p[j] = v;
    }
}

extern "C" void kernel_launch(void* const* d_in, const int* in_sizes, int n_in,
                              void* d_out, int out_size, void* d_ws, size_t ws_size,
                              hipStream_t stream) {
    const float* xyz  = (const float*)d_in[0];
    const float* feat = (const float*)d_in[1];
    const float* seed = (const float*)d_in[2];
    const float* w1 = (const float*)d_in[3];
    const float* g1 = (const float*)d_in[4];
    const float* be1 = (const float*)d_in[5];
    const float* w2 = (const float*)d_in[6];
    const float* g2 = (const float*)d_in[7];
    const float* be2 = (const float*)d_in[8];
    const float* w3 = (const float*)d_in[9];
    const float* g3 = (const float*)d_in[10];
    const float* be3 = (const float*)d_in[11];

    float* out_newxyz = (float*)d_out;                 // (B,NP,3)
    float* out_feat   = out_newxyz + B * NP * 3;       // (B,HID,NP)
    float* out_inds   = out_feat + B * HID * NP;       // (B,NP) as float

    float* stats = (float*)d_ws;                       // 3 layers x NREP x [sum(128)|sq(128)]
    int*   inds  = (int*)(stats + 3 * LSTRIDE);
    int*   idx   = inds + B * NP;
    unsigned short* w1fb  = (unsigned short*)(idx + (size_t)B * NP * NS);
    unsigned short* w2b   = w1fb + 256 * HID;
    unsigned short* w3b   = w2b + HID * HID;
    unsigned short* featT = w3b + HID * HID;           // B*N*256 bf16
    unsigned short* y1    = featT + (size_t)B * N * 256;   // S*128 bf16
    unsigned short* y2    = featT;                     // alias: featT dead after gemm1

    size_t need = (size_t)(3 * LSTRIDE) * 4 + (size_t)B * NP * 4 + (size_t)B * NP * NS * 4
                + (size_t)(256 * HID + 2 * HID * HID) * 2
                + 2ull * (size_t)B * N * 256 * 2;
    if (ws_size < need) return;

    fused_front_kernel<<<FPS_BLOCKS + TR_BLOCKS + PREP_BLOCKS, 512, 0, stream>>>(
        seed, xyz, feat, w1, w2, w3, featT, w1fb, w2b, w3b, stats,
        inds, out_newxyz, out_inds);
    ballquery_kernel<<<B * 32, 256, 0, stream>>>(xyz, out_newxyz, idx);
    gemm1_mfma<<<S / 128, 256, 0, stream>>>(w1fb, w1, featT, out_newxyz, xyz, idx, y1, stats);
    gemm_bn_mfma<<<S / 128, 256, 0, stream>>>(w2b, y1, stats, g1, be1, stats + LSTRIDE, y2);
    gemm3_pool_mfma<<<S / 128, 256, 0, stream>>>(w3b, y2, stats + LSTRIDE, g2, be2, stats + 2 * LSTRIDE, out_feat);
    finalize_kernel<<<(B * HID * NP) / 4096, 256, 0, stream>>>(out_feat, stats + 2 * LSTRIDE, g3, be3);
}